// Round 4
// baseline (293.956 us; speedup 1.0000x reference)
//
#include <hip/hip_runtime.h>
#include <hip/hip_bf16.h>
#include <math.h>

#define B_   2
#define S_   2048
#define D_   2048
#define H_   16
#define KVH_ 4
#define HD_  128
#define SCALE 0.08838834764831845f
#define LOG2E 1.44269504088896f
#define EPS_  1e-6f

typedef unsigned short u16;
typedef unsigned int   u32;
typedef __attribute__((ext_vector_type(8)))  short bf16x8;   // 8 bf16 (4 VGPRs)
typedef __attribute__((ext_vector_type(4)))  float f32x4;
typedef __attribute__((ext_vector_type(16))) float f32x16;

__device__ __forceinline__ u16 f2bf(float x) {
    union { float f; unsigned int u; } v; v.f = x;
    unsigned int r = v.u + 0x7fffu + ((v.u >> 16) & 1u);
    return (u16)(r >> 16);
}
__device__ __forceinline__ float bf2f(u16 b) {
    union { float f; unsigned int u; } v; v.u = ((unsigned int)b) << 16;
    return v.f;
}
__device__ __forceinline__ u32 cvtpk(float lo, float hi) {
    u32 r;
    asm("v_cvt_pk_bf16_f32 %0, %1, %2" : "=v"(r) : "v"(lo), "v"(hi));
    return r;
}
// async global->LDS, 16B per lane. LDS dest = uniform base + lane*16 (linear);
// swizzle applied on the per-lane GLOBAL source address (rule 21).
__device__ __forceinline__ void gload16(const void* g, void* lds) {
    __builtin_amdgcn_global_load_lds(
        (const __attribute__((address_space(1))) unsigned int*)g,
        (__attribute__((address_space(3))) unsigned int*)lds, 16, 0, 0);
}

// ---------------------------------------------------------------------------
// fp32 -> bf16 convert, all 5 arrays in one launch (blockIdx.y = segment)
// ---------------------------------------------------------------------------
__global__ __launch_bounds__(256) void f2b_all(
    const float* __restrict__ s0, u16* __restrict__ d0, int n0,
    const float* __restrict__ s1, u16* __restrict__ d1, int n1,
    const float* __restrict__ s2, u16* __restrict__ d2, int n2,
    const float* __restrict__ s3, u16* __restrict__ d3, int n3,
    const float* __restrict__ s4, u16* __restrict__ d4, int n4)
{
    const float* s; u16* d; int n;
    switch (blockIdx.y) {
        case 0: s = s0; d = d0; n = n0; break;
        case 1: s = s1; d = d1; n = n1; break;
        case 2: s = s2; d = d2; n = n2; break;
        case 3: s = s3; d = d3; n = n3; break;
        default: s = s4; d = d4; n = n4; break;
    }
    int i = blockIdx.x * 256 + threadIdx.x;
    if (i >= n) return;
    float4 v = ((const float4*)s)[i];
    ushort4 o = make_ushort4(f2bf(v.x), f2bf(v.y), f2bf(v.z), f2bf(v.w));
    ((ushort4*)d)[i] = o;
}

// ---------------------------------------------------------------------------
// bf16 MFMA GEMM (m97 structure): 128x128 tile, BK=64, 4 waves.
// MODE 0: QKV projection.  Q/K blocks: fused RMSNorm+RoPE epilogue via LDS
//         round-trip (error-neutral: same bf16 rounding count as separate
//         kernel).  V blocks: transposed scatter [kvh][d][s].
// MODE 1: O projection, fp32 output.
// ---------------------------------------------------------------------------
template<int MODE>
__global__ __launch_bounds__(256) void gemm_bf16(
    const u16* __restrict__ A,    // [4096][2048] bf16
    const u16* __restrict__ Bw,   // [N][2048] bf16 (rows = output cols)
    u16* __restrict__ Qo, u16* __restrict__ Ko, u16* __restrict__ Vt,
    float* __restrict__ Co,
    const float* __restrict__ cosb, const float* __restrict__ sinb,
    const float* __restrict__ qnw, const float* __restrict__ knw)
{
    __shared__ u16 smem[17408];         // As[8192] | Bs[8192]; aliased as Cs[128][136]
    u16* As = smem;
    u16* Bs = smem + 8192;

    const int t  = threadIdx.x;
    const int w  = t >> 6, l = t & 63;
    const int wm = w >> 1, wn = w & 1;
    const int lr = l & 15, lh = l >> 4;
    const int n0 = blockIdx.x * 128;
    const int m0 = blockIdx.y * 128;

    f32x4 acc[4][4];
    #pragma unroll
    for (int i = 0; i < 4; ++i)
        #pragma unroll
        for (int j = 0; j < 4; ++j)
            acc[i][j] = (f32x4)0.f;

    const int x = (w * 4) * 1024 + l * 16;
    for (int k0 = 0; k0 < 2048; k0 += 64) {
        #pragma unroll
        for (int u = 0; u < 4; ++u) {
            int xb = x + u * 1024;
            int r  = xb >> 7;
            int c  = xb & 127;
            int cs = c ^ ((r & 7) << 4);
            gload16(&A[(size_t)(m0 + r) * 2048 + k0 + (cs >> 1)], &As[(w * 4 + u) * 512]);
            gload16(&Bw[(size_t)(n0 + r) * 2048 + k0 + (cs >> 1)], &Bs[(w * 4 + u) * 512]);
        }
        __syncthreads();
        #pragma unroll
        for (int kc = 0; kc < 2; ++kc) {
            bf16x8 af[4], bfr[4];
            #pragma unroll
            for (int i = 0; i < 4; ++i) {
                int row = wm * 64 + i * 16 + lr;
                int byt = row * 128 + ((kc * 64 + lh * 16) ^ ((row & 7) << 4));
                af[i] = *(const bf16x8*)&As[byt >> 1];
                int rob = wn * 64 + i * 16 + lr;
                int byb = rob * 128 + ((kc * 64 + lh * 16) ^ ((rob & 7) << 4));
                bfr[i] = *(const bf16x8*)&Bs[byb >> 1];
            }
            #pragma unroll
            for (int i = 0; i < 4; ++i)
                #pragma unroll
                for (int j = 0; j < 4; ++j)
                    acc[i][j] = __builtin_amdgcn_mfma_f32_16x16x32_bf16(
                        af[i], bfr[j], acc[i][j], 0, 0, 0);
        }
        __syncthreads();
    }

    // epilogue.  C/D layout: row = (l>>4)*4 + reg, col = l&15
    if (MODE == 1) {
        #pragma unroll
        for (int i = 0; i < 4; ++i)
            #pragma unroll
            for (int j = 0; j < 4; ++j) {
                int col = n0 + wn * 64 + j * 16 + lr;
                #pragma unroll
                for (int r = 0; r < 4; ++r) {
                    int m = m0 + wm * 64 + i * 16 + lh * 4 + r;
                    Co[(size_t)m * 2048 + col] = acc[i][j][r];
                }
            }
    } else if (n0 >= 2560) {
        // V: transposed scatter [b*kvh][d][s]
        #pragma unroll
        for (int i = 0; i < 4; ++i)
            #pragma unroll
            for (int j = 0; j < 4; ++j) {
                int c2 = n0 - 2560 + wn * 64 + j * 16 + lr;
                int hh = c2 >> 7, d = c2 & 127;
                #pragma unroll
                for (int r = 0; r < 4; ++r) {
                    int m = m0 + wm * 64 + i * 16 + lh * 4 + r;
                    int bb = m >> 11, s = m & 2047;
                    Vt[((size_t)(bb * KVH_ + hh) * HD_ + d) * S_ + s] =
                        f2bf(acc[i][j][r]);
                }
            }
    } else {
        // Q or K: stage bf16 tile into LDS, then fused RMSNorm + RoPE
        #pragma unroll
        for (int i = 0; i < 4; ++i)
            #pragma unroll
            for (int j = 0; j < 4; ++j) {
                int col = wn * 64 + j * 16 + lr;
                #pragma unroll
                for (int r = 0; r < 4; ++r) {
                    int row = wm * 64 + i * 16 + lh * 4 + r;
                    smem[row * 136 + col] = f2bf(acc[i][j][r]);
                }
            }
        __syncthreads();
        if (t < 128) {
            const int row = t;
            const int m   = m0 + row;
            const int bb  = m >> 11, s = m & 2047;
            const bool isQ = (n0 < 2048);
            const int hh  = isQ ? (n0 >> 7) : ((n0 - 2048) >> 7);
            const float* wnp = isQ ? qnw : knw;
            const float scl  = isQ ? (SCALE * LOG2E) : 1.f;
            const u16* cr = &smem[row * 136];
            float ss = 0.f;
            #pragma unroll
            for (int kk = 0; kk < 16; ++kk) {
                bf16x8 vv = *(const bf16x8*)&cr[kk * 8];
                #pragma unroll
                for (int e = 0; e < 8; ++e) {
                    float xv = bf2f((u16)vv[e]); ss += xv * xv;
                }
            }
            float rr = rsqrtf(ss * (1.f / 128.f) + EPS_);
            u16* dst = isQ ? &Qo[((size_t)(bb * H_ + hh) * S_ + s) * HD_]
                           : &Ko[((size_t)(bb * KVH_ + hh) * S_ + s) * HD_];
            const float* cp = cosb + s * HD_;
            const float* sp = sinb + s * HD_;
            #pragma unroll
            for (int kk = 0; kk < 8; ++kk) {
                bf16x8 vlo = *(const bf16x8*)&cr[kk * 8];
                bf16x8 vhi = *(const bf16x8*)&cr[64 + kk * 8];
                union { u16 a[8]; bf16x8 v; } olo, ohi;
                #pragma unroll
                for (int e = 0; e < 8; ++e) {
                    int d = kk * 8 + e;
                    float nlo = bf2f((u16)vlo[e]) * rr * wnp[d];
                    float nhi = bf2f((u16)vhi[e]) * rr * wnp[d + 64];
                    olo.a[e] = f2bf((nlo * cp[d]      - nhi * sp[d])      * scl);
                    ohi.a[e] = f2bf((nhi * cp[d + 64] + nlo * sp[d + 64]) * scl);
                }
                *(bf16x8*)&dst[kk * 8]      = olo.v;
                *(bf16x8*)&dst[64 + kk * 8] = ohi.v;
            }
        }
    }
}

// ---------------------------------------------------------------------------
// Flash attention (m214 structure): 4 warps x 32 q-rows, KVBLK=64, swapped
// QK^T, in-register softmax w/ defer-max, cvt_pk+shfl P repack, dbuf swizzled
// KV staging via incremental pointers, setprio around MFMA, XCD-chunked grid.
// ---------------------------------------------------------------------------
__global__ __launch_bounds__(256, 2) void attn_mfma(
    const u16* __restrict__ Q,    // [B*H][S][128], SCALE*LOG2E pre-folded
    const u16* __restrict__ K,    // [B*KVH][S][128]
    const u16* __restrict__ Vt,   // [B*KVH][128][S]
    u16* __restrict__ AO)         // [B][S][2048]
{
    __shared__ u16 Ks[2][64 * 128];     // rows 256B, XOR-swizzled
    __shared__ u16 Vs[2][128 * 64];     // rows 128B, XOR-swizzled

    const int t  = threadIdx.x, w = t >> 6, l = t & 63;
    const int lq = l & 31, hi = l >> 5;
    // XCD-chunked swizzle: 512 blocks, 64/XCD = one (b,kvh) per XCD
    const int id = (blockIdx.x & 7) * 64 + (blockIdx.x >> 3);
    const int qx = id & 15, bh = id >> 4;
    const int bb = bh >> 4, h = bh & 15;
    const int kv = bb * KVH_ + (h >> 2);
    const int q0 = qx * 128 + w * 32;

    const u16* Qp = Q + ((size_t)bh * S_ + q0) * HD_;
    const u16* Kp = K + (size_t)kv * S_ * HD_;
    const u16* Vp = Vt + (size_t)kv * HD_ * S_;

    // Q as B-operand fragments: col=q=lane&31, k-elem j -> d = ks*16 + hi*8 + j
    bf16x8 aq[8];
    #pragma unroll
    for (int ks = 0; ks < 8; ++ks)
        aq[ks] = *(const bf16x8*)&Qp[(size_t)lq * 128 + ks * 16 + hi * 8];

    // staging pointers, hoisted; advanced incrementally per tile
    const u16* kptr[4];
    const u16* vptr[4];
    #pragma unroll
    for (int u = 0; u < 4; ++u) {
        int xb = (w * 4 + u) * 1024 + l * 16;
        int rk = xb >> 8, ck = xb & 255;
        kptr[u] = &Kp[(size_t)rk * 128 + ((ck ^ ((rk & 7) << 4)) >> 1)];
        int rv = xb >> 7, cv = xb & 127;
        vptr[u] = &Vp[(size_t)rv * S_ + ((cv ^ ((rv & 7) << 4)) >> 1)];
    }

    f32x16 oacc[4];
    #pragma unroll
    for (int dt = 0; dt < 4; ++dt) oacc[dt] = (f32x16)0.f;
    float mrun = -1e30f, lrun = 0.f;

    auto stage = [&](int buf) {
        #pragma unroll
        for (int u = 0; u < 4; ++u) {
            gload16(kptr[u], &Ks[buf][(w * 4 + u) * 512]);
            gload16(vptr[u], &Vs[buf][(w * 4 + u) * 512]);
            kptr[u] += 64 * 128;   // next K tile: 64 rows
            vptr[u] += 64;         // next V tile: 64 k-cols
        }
    };

    stage(0);
    __syncthreads();

    const int NT = S_ / 64;
    #pragma unroll 2
    for (int kt = 0; kt < NT; ++kt) {
        const int cur = kt & 1;
        if (kt + 1 < NT) stage(cur ^ 1);

        // --- swapped QK^T: S^T[k][q], A=K, B=Q ---
        f32x16 sacc[2];
        sacc[0] = (f32x16)0.f; sacc[1] = (f32x16)0.f;
        __builtin_amdgcn_s_setprio(1);
        #pragma unroll
        for (int kb = 0; kb < 2; ++kb) {
            #pragma unroll
            for (int ks = 0; ks < 8; ++ks) {
                int row = kb * 32 + lq;
                int byt = row * 256 + ((ks * 32 + hi * 16) ^ ((row & 7) << 4));
                bf16x8 kf = *(const bf16x8*)&Ks[cur][byt >> 1];
                sacc[kb] = __builtin_amdgcn_mfma_f32_32x32x16_bf16(
                    kf, aq[ks], sacc[kb], 0, 0, 0);
            }
        }
        __builtin_amdgcn_s_setprio(0);

        // --- in-register online softmax (lane owns q-row lq; halves split k) ---
        float mx = -1e30f;
        #pragma unroll
        for (int r = 0; r < 16; ++r)
            mx = fmaxf(mx, fmaxf(sacc[0][r], sacc[1][r]));
        mx = fmaxf(mx, __shfl_xor(mx, 32));
        if (__any(mx > mrun + 8.f)) {           // defer-max (T13)
            float mn = fmaxf(mrun, mx);
            float al = __builtin_exp2f(mrun - mn);
            mrun = mn;
            lrun *= al;
            #pragma unroll
            for (int r = 0; r < 16; ++r) {
                int src = (r & 3) + 8 * (r >> 2) + 4 * hi;   // output-row owner
                float alr = __shfl(al, src);
                #pragma unroll
                for (int dt = 0; dt < 4; ++dt) oacc[dt][r] *= alr;
            }
        }
        float ps = 0.f;
        #pragma unroll
        for (int kb = 0; kb < 2; ++kb)
            #pragma unroll
            for (int r = 0; r < 16; ++r) {
                float p = __builtin_exp2f(sacc[kb][r] - mrun);
                sacc[kb][r] = p;
                ps += p;
            }
        ps += __shfl_xor(ps, 32);
        lrun += ps;

        // --- P repack (cvt_pk + cross-half exchange) and PV ---
        #pragma unroll
        for (int kb = 0; kb < 2; ++kb) {
            u32 wv[8], sv[8];
            #pragma unroll
            for (int i = 0; i < 8; ++i)
                wv[i] = cvtpk(sacc[kb][2 * i], sacc[kb][2 * i + 1]);
            #pragma unroll
            for (int i = 0; i < 8; ++i)
                sv[i] = __shfl_xor(wv[i], 32);
            #pragma unroll
            for (int k2 = 0; k2 < 2; ++k2) {
                union { u32 u[4]; bf16x8 v; } pa;
                pa.u[0] = hi ? sv[4 * k2 + 2] : wv[4 * k2 + 0];
                pa.u[1] = hi ? sv[4 * k2 + 3] : wv[4 * k2 + 1];
                pa.u[2] = hi ? wv[4 * k2 + 2] : sv[4 * k2 + 0];
                pa.u[3] = hi ? wv[4 * k2 + 3] : sv[4 * k2 + 1];
                int kloc = (kb * 2 + k2) * 16 + hi * 8;      // V k-slice base
                __builtin_amdgcn_s_setprio(1);
                #pragma unroll
                for (int dt = 0; dt < 4; ++dt) {
                    int rowv = dt * 32 + lq;
                    int byv  = rowv * 128 + ((kloc * 2) ^ ((rowv & 7) << 4));
                    bf16x8 vf = *(const bf16x8*)&Vs[cur][byv >> 1];
                    oacc[dt] = __builtin_amdgcn_mfma_f32_32x32x16_bf16(
                        pa.v, vf, oacc[dt], 0, 0, 0);
                }
                __builtin_amdgcn_s_setprio(0);
            }
        }
        __syncthreads();
    }

    // epilogue: O[q'][d], q' = (r&3)+8*(r>>2)+4*hi, d = dt*32+lq
    #pragma unroll
    for (int r = 0; r < 16; ++r) {
        int src = (r & 3) + 8 * (r >> 2) + 4 * hi;
        float linv = 1.f / __shfl(lrun, src);
        int s = q0 + src;
        size_t base = ((size_t)bb * S_ + s) * 2048 + h * 128 + lq;
        #pragma unroll
        for (int dt = 0; dt < 4; ++dt)
            AO[base + dt * 32] = f2bf(oacc[dt][r] * linv);
    }
}

// ---------------------------------------------------------------------------
extern "C" void kernel_launch(void* const* d_in, const int* in_sizes, int n_in,
                              void* d_out, int out_size, void* d_ws, size_t ws_size,
                              hipStream_t stream) {
    (void)in_sizes; (void)n_in; (void)out_size; (void)ws_size;
    const float* hid  = (const float*)d_in[0];
    const float* cosb = (const float*)d_in[1];
    const float* sinb = (const float*)d_in[2];
    const float* qw   = (const float*)d_in[3];
    const float* kw   = (const float*)d_in[4];
    const float* vw   = (const float*)d_in[5];
    const float* ow   = (const float*)d_in[6];
    const float* qnw  = (const float*)d_in[7];
    const float* knw  = (const float*)d_in[8];

    u16* ws   = (u16*)d_ws;
    u16* hidB = ws;                         // 8,388,608
    u16* Wc   = ws + 8388608;               // 6,291,456  (qw|kw|vw rows)
    u16* owB  = ws + 14680064;              // 4,194,304
    u16* Qb   = ws + 18874368;              // 8,388,608  [B*H][S][128]
    u16* Kb   = ws + 27262976;              // 2,097,152  [B*KVH][S][128]
    u16* VtB  = ws + 29360128;              // 2,097,152  [B*KVH][128][S]
    u16* AO   = ws + 31457280;              // 8,388,608  [B][S][2048]

    f2b_all<<<dim3(8192, 5), 256, 0, stream>>>(
        hid, hidB, 2097152,
        qw,  Wc,            1048576,
        kw,  Wc + 4194304,  262144,
        vw,  Wc + 5242880,  262144,
        ow,  owB,           1048576);

    gemm_bf16<0><<<dim3(24, 32), 256, 0, stream>>>(
        hidB, Wc, Qb, Kb, VtB, nullptr, cosb, sinb, qnw, knw);
    attn_mfma<<<512, 256, 0, stream>>>(Qb, Kb, VtB, AO);
    gemm_bf16<1><<<dim3(16, 32), 256, 0, stream>>>(
        AO, owB, nullptr, nullptr, nullptr, (float*)d_out,
        nullptr, nullptr, nullptr, nullptr);
}

// Round 5
// 242.984 us; speedup vs baseline: 1.2098x; 1.2098x over previous
//
#include <hip/hip_runtime.h>
#include <hip/hip_bf16.h>
#include <math.h>

#define B_   2
#define S_   2048
#define D_   2048
#define H_   16
#define KVH_ 4
#define HD_  128
#define SCALE 0.08838834764831845f
#define LOG2E 1.44269504088896f
#define EPS_  1e-6f

typedef unsigned short u16;
typedef unsigned int   u32;
typedef __attribute__((ext_vector_type(8)))  short bf16x8;   // 8 bf16 (4 VGPRs)
typedef __attribute__((ext_vector_type(4)))  float f32x4;
typedef __attribute__((ext_vector_type(16))) float f32x16;

__device__ __forceinline__ u16 f2bf(float x) {
    union { float f; unsigned int u; } v; v.f = x;
    unsigned int r = v.u + 0x7fffu + ((v.u >> 16) & 1u);
    return (u16)(r >> 16);
}
__device__ __forceinline__ float bf2f(u16 b) {
    union { float f; unsigned int u; } v; v.u = ((unsigned int)b) << 16;
    return v.f;
}
__device__ __forceinline__ u32 cvtpk(float lo, float hi) {
    u32 r;
    asm("v_cvt_pk_bf16_f32 %0, %1, %2" : "=v"(r) : "v"(lo), "v"(hi));
    return r;
}
// async global->LDS, 16B per lane. LDS dest = uniform base + lane*16 (linear);
// swizzle applied on the per-lane GLOBAL source address (rule 21).
__device__ __forceinline__ void gload16(const void* g, void* lds) {
    __builtin_amdgcn_global_load_lds(
        (const __attribute__((address_space(1))) unsigned int*)g,
        (__attribute__((address_space(3))) unsigned int*)lds, 16, 0, 0);
}

// ---------------------------------------------------------------------------
// fp32 -> bf16 convert, all 5 arrays in one launch (blockIdx.y = segment)
// ---------------------------------------------------------------------------
__global__ __launch_bounds__(256) void f2b_all(
    const float* __restrict__ s0, u16* __restrict__ d0, int n0,
    const float* __restrict__ s1, u16* __restrict__ d1, int n1,
    const float* __restrict__ s2, u16* __restrict__ d2, int n2,
    const float* __restrict__ s3, u16* __restrict__ d3, int n3,
    const float* __restrict__ s4, u16* __restrict__ d4, int n4)
{
    const float* s; u16* d; int n;
    switch (blockIdx.y) {
        case 0: s = s0; d = d0; n = n0; break;
        case 1: s = s1; d = d1; n = n1; break;
        case 2: s = s2; d = d2; n = n2; break;
        case 3: s = s3; d = d3; n = n3; break;
        default: s = s4; d = d4; n = n4; break;
    }
    int i = blockIdx.x * 256 + threadIdx.x;
    if (i >= n) return;
    float4 v = ((const float4*)s)[i];
    ushort4 o = make_ushort4(f2bf(v.x), f2bf(v.y), f2bf(v.z), f2bf(v.w));
    ((ushort4*)d)[i] = o;
}

// ---------------------------------------------------------------------------
// bf16 MFMA GEMM, m97 structure: 128x128 tile, BK=64, 4 waves (2x2 of 64x64),
// global_load_lds w=16 with pre-swizzled source; XOR-swizzled ds_read_b128.
// MODE 0: QKV projection with head-major scatter epilogue (V transposed).
// MODE 1: O projection, fp32 output.
// ---------------------------------------------------------------------------
template<int MODE>
__global__ __launch_bounds__(256) void gemm_bf16(
    const u16* __restrict__ A,    // [4096][2048] bf16
    const u16* __restrict__ Bw,   // [N][2048] bf16 (rows = output cols)
    u16* __restrict__ Qo, u16* __restrict__ Ko, u16* __restrict__ Vt,
    float* __restrict__ Co)
{
    __shared__ u16 As[128 * 64];
    __shared__ u16 Bs[128 * 64];

    const int t  = threadIdx.x;
    const int w  = t >> 6, l = t & 63;
    const int wm = w >> 1, wn = w & 1;
    const int lr = l & 15, lh = l >> 4;
    const int n0 = blockIdx.x * 128;
    const int m0 = blockIdx.y * 128;

    f32x4 acc[4][4];
    #pragma unroll
    for (int i = 0; i < 4; ++i)
        #pragma unroll
        for (int j = 0; j < 4; ++j)
            acc[i][j] = (f32x4)0.f;

    const int x = (w * 4) * 1024 + l * 16;
    for (int k0 = 0; k0 < 2048; k0 += 64) {
        #pragma unroll
        for (int u = 0; u < 4; ++u) {
            int xb = x + u * 1024;
            int r  = xb >> 7;
            int c  = xb & 127;
            int cs = c ^ ((r & 7) << 4);
            gload16(&A[(size_t)(m0 + r) * 2048 + k0 + (cs >> 1)], &As[(w * 4 + u) * 512]);
            gload16(&Bw[(size_t)(n0 + r) * 2048 + k0 + (cs >> 1)], &Bs[(w * 4 + u) * 512]);
        }
        __syncthreads();
        #pragma unroll
        for (int kc = 0; kc < 2; ++kc) {
            bf16x8 af[4], bfr[4];
            #pragma unroll
            for (int i = 0; i < 4; ++i) {
                int row = wm * 64 + i * 16 + lr;
                int byt = row * 128 + ((kc * 64 + lh * 16) ^ ((row & 7) << 4));
                af[i] = *(const bf16x8*)&As[byt >> 1];
                int rob = wn * 64 + i * 16 + lr;
                int byb = rob * 128 + ((kc * 64 + lh * 16) ^ ((rob & 7) << 4));
                bfr[i] = *(const bf16x8*)&Bs[byb >> 1];
            }
            #pragma unroll
            for (int i = 0; i < 4; ++i)
                #pragma unroll
                for (int j = 0; j < 4; ++j)
                    acc[i][j] = __builtin_amdgcn_mfma_f32_16x16x32_bf16(
                        af[i], bfr[j], acc[i][j], 0, 0, 0);
        }
        __syncthreads();
    }

    // epilogue.  C/D layout: row = (l>>4)*4 + reg, col = l&15
    #pragma unroll
    for (int i = 0; i < 4; ++i) {
        #pragma unroll
        for (int j = 0; j < 4; ++j) {
            int col = n0 + wn * 64 + j * 16 + lr;
            #pragma unroll
            for (int r = 0; r < 4; ++r) {
                int m = m0 + wm * 64 + i * 16 + lh * 4 + r;
                float v = acc[i][j][r];
                if (MODE == 0) {
                    int bb = m >> 11, s = m & 2047;
                    if (col < 2048) {
                        int hh = col >> 7, d = col & 127;
                        Qo[((size_t)(bb * H_ + hh) * S_ + s) * HD_ + d] = f2bf(v);
                    } else if (col < 2560) {
                        int c2 = col - 2048; int hh = c2 >> 7, d = c2 & 127;
                        Ko[((size_t)(bb * KVH_ + hh) * S_ + s) * HD_ + d] = f2bf(v);
                    } else {
                        int c2 = col - 2560; int hh = c2 >> 7, d = c2 & 127;
                        Vt[((size_t)(bb * KVH_ + hh) * HD_ + d) * S_ + s] = f2bf(v);
                    }
                } else {
                    Co[(size_t)m * 2048 + col] = v;
                }
            }
        }
    }
}

// ---------------------------------------------------------------------------
// RMSNorm + RoPE in place (bf16).  One wave per 128-elem row.
// Q gets SCALE*LOG2E folded (attention uses exp2 directly).
// ---------------------------------------------------------------------------
__global__ __launch_bounds__(256) void norm_rope(
    u16* __restrict__ Qb, u16* __restrict__ Kb,
    const float* __restrict__ cosb, const float* __restrict__ sinb,
    const float* __restrict__ qnw, const float* __restrict__ knw)
{
    const int rid = blockIdx.x * 4 + (threadIdx.x >> 6);
    const int l   = threadIdx.x & 63;
    u16* row; const float* wn; int s; float sc;
    if (rid < B_ * H_ * S_) {
        row = Qb + (size_t)rid * HD_; wn = qnw; s = rid & (S_ - 1); sc = SCALE * LOG2E;
    } else {
        int r2 = rid - B_ * H_ * S_;
        row = Kb + (size_t)r2 * HD_; wn = knw; s = r2 & (S_ - 1); sc = 1.f;
    }
    unsigned int u = *(const unsigned int*)&row[2 * l];
    float x0 = bf2f((u16)(u & 0xffff)), x1 = bf2f((u16)(u >> 16));
    float ss = x0 * x0 + x1 * x1;
    #pragma unroll
    for (int off = 1; off < 64; off <<= 1) ss += __shfl_xor(ss, off);
    float rr = rsqrtf(ss * (1.f / 128.f) + 1e-6f);
    float n0 = x0 * rr * wn[2 * l];
    float n1 = x1 * rr * wn[2 * l + 1];
    float p0 = __shfl_xor(n0, 32);
    float p1 = __shfl_xor(n1, 32);
    float sg = (l < 32) ? -1.f : 1.f;
    const float* cp = cosb + s * HD_;
    const float* sp = sinb + s * HD_;
    float o0 = (n0 * cp[2 * l]     + sg * p0 * sp[2 * l])     * sc;
    float o1 = (n1 * cp[2 * l + 1] + sg * p1 * sp[2 * l + 1]) * sc;
    unsigned int o = (unsigned int)f2bf(o0) | ((unsigned int)f2bf(o1) << 16);
    *(unsigned int*)&row[2 * l] = o;
}

// ---------------------------------------------------------------------------
// Flash attention (m214 structure): 4 warps x 32 q-rows, KVBLK=64, swapped
// QK^T, in-register softmax w/ defer-max, cvt_pk+shfl P repack, dbuf swizzled
// KV staging via incremental pointers, setprio around MFMA, XCD-chunked grid.
// ---------------------------------------------------------------------------
__global__ __launch_bounds__(256, 2) void attn_mfma(
    const u16* __restrict__ Q,    // [B*H][S][128], SCALE*LOG2E pre-folded
    const u16* __restrict__ K,    // [B*KVH][S][128]
    const u16* __restrict__ Vt,   // [B*KVH][128][S]
    u16* __restrict__ AO)         // [B][S][2048]
{
    __shared__ u16 Ks[2][64 * 128];     // rows 256B, XOR-swizzled
    __shared__ u16 Vs[2][128 * 64];     // rows 128B, XOR-swizzled

    const int t  = threadIdx.x, w = t >> 6, l = t & 63;
    const int lq = l & 31, hi = l >> 5;
    // XCD-chunked swizzle: 512 blocks, 64/XCD = one (b,kvh) per XCD
    const int id = (blockIdx.x & 7) * 64 + (blockIdx.x >> 3);
    const int qx = id & 15, bh = id >> 4;
    const int bb = bh >> 4, h = bh & 15;
    const int kv = bb * KVH_ + (h >> 2);
    const int q0 = qx * 128 + w * 32;

    const u16* Qp = Q + ((size_t)bh * S_ + q0) * HD_;
    const u16* Kp = K + (size_t)kv * S_ * HD_;
    const u16* Vp = Vt + (size_t)kv * HD_ * S_;

    // Q as B-operand fragments: col=q=lane&31, k-elem j -> d = ks*16 + hi*8 + j
    bf16x8 aq[8];
    #pragma unroll
    for (int ks = 0; ks < 8; ++ks)
        aq[ks] = *(const bf16x8*)&Qp[(size_t)lq * 128 + ks * 16 + hi * 8];

    // staging pointers, hoisted; advanced incrementally per tile
    const u16* kptr[4];
    const u16* vptr[4];
    #pragma unroll
    for (int u = 0; u < 4; ++u) {
        int xb = (w * 4 + u) * 1024 + l * 16;
        int rk = xb >> 8, ck = xb & 255;
        kptr[u] = &Kp[(size_t)rk * 128 + ((ck ^ ((rk & 7) << 4)) >> 1)];
        int rv = xb >> 7, cv = xb & 127;
        vptr[u] = &Vp[(size_t)rv * S_ + ((cv ^ ((rv & 7) << 4)) >> 1)];
    }

    f32x16 oacc[4];
    #pragma unroll
    for (int dt = 0; dt < 4; ++dt) oacc[dt] = (f32x16)0.f;
    float mrun = -1e30f, lrun = 0.f;

    auto stage = [&](int buf) {
        #pragma unroll
        for (int u = 0; u < 4; ++u) {
            gload16(kptr[u], &Ks[buf][(w * 4 + u) * 512]);
            gload16(vptr[u], &Vs[buf][(w * 4 + u) * 512]);
            kptr[u] += 64 * 128;   // next K tile: 64 rows
            vptr[u] += 64;         // next V tile: 64 k-cols
        }
    };

    stage(0);
    __syncthreads();

    const int NT = S_ / 64;
    #pragma unroll 2
    for (int kt = 0; kt < NT; ++kt) {
        const int cur = kt & 1;
        if (kt + 1 < NT) stage(cur ^ 1);

        // --- swapped QK^T: S^T[k][q], A=K, B=Q ---
        f32x16 sacc[2];
        sacc[0] = (f32x16)0.f; sacc[1] = (f32x16)0.f;
        __builtin_amdgcn_s_setprio(1);
        #pragma unroll
        for (int kb = 0; kb < 2; ++kb) {
            #pragma unroll
            for (int ks = 0; ks < 8; ++ks) {
                int row = kb * 32 + lq;
                int byt = row * 256 + ((ks * 32 + hi * 16) ^ ((row & 7) << 4));
                bf16x8 kf = *(const bf16x8*)&Ks[cur][byt >> 1];
                sacc[kb] = __builtin_amdgcn_mfma_f32_32x32x16_bf16(
                    kf, aq[ks], sacc[kb], 0, 0, 0);
            }
        }
        __builtin_amdgcn_s_setprio(0);

        // --- in-register online softmax (lane owns q-row lq; halves split k) ---
        float mx = -1e30f;
        #pragma unroll
        for (int r = 0; r < 16; ++r)
            mx = fmaxf(mx, fmaxf(sacc[0][r], sacc[1][r]));
        mx = fmaxf(mx, __shfl_xor(mx, 32));
        if (__any(mx > mrun + 8.f)) {           // defer-max (T13)
            float mn = fmaxf(mrun, mx);
            float al = __builtin_exp2f(mrun - mn);
            mrun = mn;
            lrun *= al;
            #pragma unroll
            for (int r = 0; r < 16; ++r) {
                int src = (r & 3) + 8 * (r >> 2) + 4 * hi;   // output-row owner
                float alr = __shfl(al, src);
                #pragma unroll
                for (int dt = 0; dt < 4; ++dt) oacc[dt][r] *= alr;
            }
        }
        float ps = 0.f;
        #pragma unroll
        for (int kb = 0; kb < 2; ++kb)
            #pragma unroll
            for (int r = 0; r < 16; ++r) {
                float p = __builtin_exp2f(sacc[kb][r] - mrun);
                sacc[kb][r] = p;
                ps += p;
            }
        ps += __shfl_xor(ps, 32);
        lrun += ps;

        // --- P repack (cvt_pk + cross-half exchange) and PV ---
        #pragma unroll
        for (int kb = 0; kb < 2; ++kb) {
            u32 wv[8], sv[8];
            #pragma unroll
            for (int i = 0; i < 8; ++i)
                wv[i] = cvtpk(sacc[kb][2 * i], sacc[kb][2 * i + 1]);
            #pragma unroll
            for (int i = 0; i < 8; ++i)
                sv[i] = __shfl_xor(wv[i], 32);
            #pragma unroll
            for (int k2 = 0; k2 < 2; ++k2) {
                union { u32 u[4]; bf16x8 v; } pa;
                pa.u[0] = hi ? sv[4 * k2 + 2] : wv[4 * k2 + 0];
                pa.u[1] = hi ? sv[4 * k2 + 3] : wv[4 * k2 + 1];
                pa.u[2] = hi ? wv[4 * k2 + 2] : sv[4 * k2 + 0];
                pa.u[3] = hi ? wv[4 * k2 + 3] : sv[4 * k2 + 1];
                int kloc = (kb * 2 + k2) * 16 + hi * 8;      // V k-slice base
                __builtin_amdgcn_s_setprio(1);
                #pragma unroll
                for (int dt = 0; dt < 4; ++dt) {
                    int rowv = dt * 32 + lq;
                    int byv  = rowv * 128 + ((kloc * 2) ^ ((rowv & 7) << 4));
                    bf16x8 vf = *(const bf16x8*)&Vs[cur][byv >> 1];
                    oacc[dt] = __builtin_amdgcn_mfma_f32_32x32x16_bf16(
                        pa.v, vf, oacc[dt], 0, 0, 0);
                }
                __builtin_amdgcn_s_setprio(0);
            }
        }
        __syncthreads();
    }

    // epilogue: O[q'][d], q' = (r&3)+8*(r>>2)+4*hi, d = dt*32+lq
    #pragma unroll
    for (int r = 0; r < 16; ++r) {
        int src = (r & 3) + 8 * (r >> 2) + 4 * hi;
        float linv = 1.f / __shfl(lrun, src);
        int s = q0 + src;
        size_t base = ((size_t)bb * S_ + s) * 2048 + h * 128 + lq;
        #pragma unroll
        for (int dt = 0; dt < 4; ++dt)
            AO[base + dt * 32] = f2bf(oacc[dt][r] * linv);
    }
}

// ---------------------------------------------------------------------------
extern "C" void kernel_launch(void* const* d_in, const int* in_sizes, int n_in,
                              void* d_out, int out_size, void* d_ws, size_t ws_size,
                              hipStream_t stream) {
    (void)in_sizes; (void)n_in; (void)out_size; (void)ws_size;
    const float* hid  = (const float*)d_in[0];
    const float* cosb = (const float*)d_in[1];
    const float* sinb = (const float*)d_in[2];
    const float* qw   = (const float*)d_in[3];
    const float* kw   = (const float*)d_in[4];
    const float* vw   = (const float*)d_in[5];
    const float* ow   = (const float*)d_in[6];
    const float* qnw  = (const float*)d_in[7];
    const float* knw  = (const float*)d_in[8];

    u16* ws   = (u16*)d_ws;
    u16* hidB = ws;                         // 8,388,608
    u16* Wc   = ws + 8388608;               // 6,291,456  (qw|kw|vw rows)
    u16* owB  = ws + 14680064;              // 4,194,304
    u16* Qb   = ws + 18874368;              // 8,388,608  [B*H][S][128]
    u16* Kb   = ws + 27262976;              // 2,097,152  [B*KVH][S][128]
    u16* VtB  = ws + 29360128;              // 2,097,152  [B*KVH][128][S]
    u16* AO   = ws + 31457280;              // 8,388,608  [B][S][2048]

    f2b_all<<<dim3(8192, 5), 256, 0, stream>>>(
        hid, hidB, 2097152,
        qw,  Wc,            1048576,
        kw,  Wc + 4194304,  262144,
        vw,  Wc + 5242880,  262144,
        ow,  owB,           1048576);

    gemm_bf16<0><<<dim3(24, 32), 256, 0, stream>>>(hidB, Wc, Qb, Kb, VtB, nullptr);
    norm_rope<<<20480, 256, 0, stream>>>(Qb, Kb, cosb, sinb, qnw, knw);
    attn_mfma<<<512, 256, 0, stream>>>(Qb, Kb, VtB, AO);
    gemm_bf16<1><<<dim3(16, 32), 256, 0, stream>>>(AO, owB, nullptr, nullptr, nullptr,
                                                   (float*)d_out);
}

// Round 6
// 236.987 us; speedup vs baseline: 1.2404x; 1.0253x over previous
//
#include <hip/hip_runtime.h>
#include <hip/hip_bf16.h>
#include <math.h>

#define B_   2
#define S_   2048
#define D_   2048
#define H_   16
#define KVH_ 4
#define HD_  128
#define SCALE 0.08838834764831845f
#define LOG2E 1.44269504088896f
#define EPS_  1e-6f

typedef unsigned short u16;
typedef unsigned int   u32;
typedef __attribute__((ext_vector_type(2)))  unsigned int u32x2;
typedef __attribute__((ext_vector_type(8)))  short bf16x8;   // 8 bf16 (4 VGPRs)
typedef __attribute__((ext_vector_type(4)))  float f32x4;
typedef __attribute__((ext_vector_type(16))) float f32x16;

__device__ __forceinline__ u16 f2bf(float x) {
    union { float f; unsigned int u; } v; v.f = x;
    unsigned int r = v.u + 0x7fffu + ((v.u >> 16) & 1u);
    return (u16)(r >> 16);
}
__device__ __forceinline__ float bf2f(u16 b) {
    union { float f; unsigned int u; } v; v.u = ((unsigned int)b) << 16;
    return v.f;
}
__device__ __forceinline__ u32 cvtpk(float lo, float hi) {
    u32 r;
    asm("v_cvt_pk_bf16_f32 %0, %1, %2" : "=v"(r) : "v"(lo), "v"(hi));
    return r;
}
// async global->LDS, 16B per lane. LDS dest = uniform base + lane*16 (linear);
// swizzle applied on the per-lane GLOBAL source address (rule 21).
__device__ __forceinline__ void gload16(const void* g, void* lds) {
    __builtin_amdgcn_global_load_lds(
        (const __attribute__((address_space(1))) unsigned int*)g,
        (__attribute__((address_space(3))) unsigned int*)lds, 16, 0, 0);
}

// ---------------------------------------------------------------------------
// fp32 -> bf16 convert, all 5 arrays in one launch (blockIdx.y = segment)
// ---------------------------------------------------------------------------
__global__ __launch_bounds__(256) void f2b_all(
    const float* __restrict__ s0, u16* __restrict__ d0, int n0,
    const float* __restrict__ s1, u16* __restrict__ d1, int n1,
    const float* __restrict__ s2, u16* __restrict__ d2, int n2,
    const float* __restrict__ s3, u16* __restrict__ d3, int n3,
    const float* __restrict__ s4, u16* __restrict__ d4, int n4)
{
    const float* s; u16* d; int n;
    switch (blockIdx.y) {
        case 0: s = s0; d = d0; n = n0; break;
        case 1: s = s1; d = d1; n = n1; break;
        case 2: s = s2; d = d2; n = n2; break;
        case 3: s = s3; d = d3; n = n3; break;
        default: s = s4; d = d4; n = n4; break;
    }
    int i = blockIdx.x * 256 + threadIdx.x;
    if (i >= n) return;
    float4 v = ((const float4*)s)[i];
    ushort4 o = make_ushort4(f2bf(v.x), f2bf(v.y), f2bf(v.z), f2bf(v.w));
    ((ushort4*)d)[i] = o;
}

// ---------------------------------------------------------------------------
// bf16 MFMA GEMM, m97 structure: 128x128 tile, BK=64, 4 waves (2x2 of 64x64),
// global_load_lds w=16 with pre-swizzled source; XOR-swizzled ds_read_b128.
// MODE 0: QKV projection with head-major scatter epilogue (V transposed).
// MODE 1: O projection, fp32 output.
// ---------------------------------------------------------------------------
template<int MODE>
__global__ __launch_bounds__(256) void gemm_bf16(
    const u16* __restrict__ A,    // [4096][2048] bf16
    const u16* __restrict__ Bw,   // [N][2048] bf16 (rows = output cols)
    u16* __restrict__ Qo, u16* __restrict__ Ko, u16* __restrict__ Vt,
    float* __restrict__ Co)
{
    __shared__ u16 As[128 * 64];
    __shared__ u16 Bs[128 * 64];

    const int t  = threadIdx.x;
    const int w  = t >> 6, l = t & 63;
    const int wm = w >> 1, wn = w & 1;
    const int lr = l & 15, lh = l >> 4;
    const int n0 = blockIdx.x * 128;
    const int m0 = blockIdx.y * 128;

    f32x4 acc[4][4];
    #pragma unroll
    for (int i = 0; i < 4; ++i)
        #pragma unroll
        for (int j = 0; j < 4; ++j)
            acc[i][j] = (f32x4)0.f;

    const int x = (w * 4) * 1024 + l * 16;
    for (int k0 = 0; k0 < 2048; k0 += 64) {
        #pragma unroll
        for (int u = 0; u < 4; ++u) {
            int xb = x + u * 1024;
            int r  = xb >> 7;
            int c  = xb & 127;
            int cs = c ^ ((r & 7) << 4);
            gload16(&A[(size_t)(m0 + r) * 2048 + k0 + (cs >> 1)], &As[(w * 4 + u) * 512]);
            gload16(&Bw[(size_t)(n0 + r) * 2048 + k0 + (cs >> 1)], &Bs[(w * 4 + u) * 512]);
        }
        __syncthreads();
        #pragma unroll
        for (int kc = 0; kc < 2; ++kc) {
            bf16x8 af[4], bfr[4];
            #pragma unroll
            for (int i = 0; i < 4; ++i) {
                int row = wm * 64 + i * 16 + lr;
                int byt = row * 128 + ((kc * 64 + lh * 16) ^ ((row & 7) << 4));
                af[i] = *(const bf16x8*)&As[byt >> 1];
                int rob = wn * 64 + i * 16 + lr;
                int byb = rob * 128 + ((kc * 64 + lh * 16) ^ ((rob & 7) << 4));
                bfr[i] = *(const bf16x8*)&Bs[byb >> 1];
            }
            #pragma unroll
            for (int i = 0; i < 4; ++i)
                #pragma unroll
                for (int j = 0; j < 4; ++j)
                    acc[i][j] = __builtin_amdgcn_mfma_f32_16x16x32_bf16(
                        af[i], bfr[j], acc[i][j], 0, 0, 0);
        }
        __syncthreads();
    }

    // epilogue.  C/D layout: row = (l>>4)*4 + reg, col = l&15
    #pragma unroll
    for (int i = 0; i < 4; ++i) {
        #pragma unroll
        for (int j = 0; j < 4; ++j) {
            int col = n0 + wn * 64 + j * 16 + lr;
            #pragma unroll
            for (int r = 0; r < 4; ++r) {
                int m = m0 + wm * 64 + i * 16 + lh * 4 + r;
                float v = acc[i][j][r];
                if (MODE == 0) {
                    int bb = m >> 11, s = m & 2047;
                    if (col < 2048) {
                        int hh = col >> 7, d = col & 127;
                        Qo[((size_t)(bb * H_ + hh) * S_ + s) * HD_ + d] = f2bf(v);
                    } else if (col < 2560) {
                        int c2 = col - 2048; int hh = c2 >> 7, d = c2 & 127;
                        Ko[((size_t)(bb * KVH_ + hh) * S_ + s) * HD_ + d] = f2bf(v);
                    } else {
                        int c2 = col - 2560; int hh = c2 >> 7, d = c2 & 127;
                        Vt[((size_t)(bb * KVH_ + hh) * HD_ + d) * S_ + s] = f2bf(v);
                    }
                } else {
                    Co[(size_t)m * 2048 + col] = v;
                }
            }
        }
    }
}

// ---------------------------------------------------------------------------
// RMSNorm + RoPE in place (bf16).  One wave per 128-elem row.
// Q gets SCALE*LOG2E folded (attention uses exp2 directly).
// ---------------------------------------------------------------------------
__global__ __launch_bounds__(256) void norm_rope(
    u16* __restrict__ Qb, u16* __restrict__ Kb,
    const float* __restrict__ cosb, const float* __restrict__ sinb,
    const float* __restrict__ qnw, const float* __restrict__ knw)
{
    const int rid = blockIdx.x * 4 + (threadIdx.x >> 6);
    const int l   = threadIdx.x & 63;
    u16* row; const float* wn; int s; float sc;
    if (rid < B_ * H_ * S_) {
        row = Qb + (size_t)rid * HD_; wn = qnw; s = rid & (S_ - 1); sc = SCALE * LOG2E;
    } else {
        int r2 = rid - B_ * H_ * S_;
        row = Kb + (size_t)r2 * HD_; wn = knw; s = r2 & (S_ - 1); sc = 1.f;
    }
    unsigned int u = *(const unsigned int*)&row[2 * l];
    float x0 = bf2f((u16)(u & 0xffff)), x1 = bf2f((u16)(u >> 16));
    float ss = x0 * x0 + x1 * x1;
    #pragma unroll
    for (int off = 1; off < 64; off <<= 1) ss += __shfl_xor(ss, off);
    float rr = rsqrtf(ss * (1.f / 128.f) + 1e-6f);
    float n0 = x0 * rr * wn[2 * l];
    float n1 = x1 * rr * wn[2 * l + 1];
    float p0 = __shfl_xor(n0, 32);
    float p1 = __shfl_xor(n1, 32);
    float sg = (l < 32) ? -1.f : 1.f;
    const float* cp = cosb + s * HD_;
    const float* sp = sinb + s * HD_;
    float o0 = (n0 * cp[2 * l]     + sg * p0 * sp[2 * l])     * sc;
    float o1 = (n1 * cp[2 * l + 1] + sg * p1 * sp[2 * l + 1]) * sc;
    unsigned int o = (unsigned int)f2bf(o0) | ((unsigned int)f2bf(o1) << 16);
    *(unsigned int*)&row[2 * l] = o;
}

// ---------------------------------------------------------------------------
// Flash attention (m214 structure, R3 body): 4 warps x 32 q-rows, KVBLK=64,
// swapped QK^T, in-register softmax w/ defer-max, cvt_pk + permlane32_swap
// P repack, dbuf swizzled KV staging, XCD-chunked grid.
// ---------------------------------------------------------------------------
__global__ __launch_bounds__(256, 2) void attn_mfma(
    const u16* __restrict__ Q,    // [B*H][S][128], SCALE*LOG2E pre-folded
    const u16* __restrict__ K,    // [B*KVH][S][128]
    const u16* __restrict__ Vt,   // [B*KVH][128][S]
    u16* __restrict__ AO)         // [B][S][2048]
{
    __shared__ u16 Ks[2][64 * 128];     // rows 256B, XOR-swizzled
    __shared__ u16 Vs[2][128 * 64];     // rows 128B, XOR-swizzled

    const int t  = threadIdx.x, w = t >> 6, l = t & 63;
    const int lq = l & 31, hi = l >> 5;
    // XCD-chunked swizzle: 512 blocks, 64/XCD = one (b,kvh) per XCD
    const int id = (blockIdx.x & 7) * 64 + (blockIdx.x >> 3);
    const int qx = id & 15, bh = id >> 4;
    const int bb = bh >> 4, h = bh & 15;
    const int kv = bb * KVH_ + (h >> 2);
    const int q0 = qx * 128 + w * 32;

    const u16* Qp = Q + ((size_t)bh * S_ + q0) * HD_;
    const u16* Kp = K + (size_t)kv * S_ * HD_;
    const u16* Vp = Vt + (size_t)kv * HD_ * S_;

    // Q as B-operand fragments: col=q=lane&31, k-elem j -> d = ks*16 + hi*8 + j
    bf16x8 aq[8];
    #pragma unroll
    for (int ks = 0; ks < 8; ++ks)
        aq[ks] = *(const bf16x8*)&Qp[(size_t)lq * 128 + ks * 16 + hi * 8];

    f32x16 oacc[4];
    #pragma unroll
    for (int dt = 0; dt < 4; ++dt) oacc[dt] = (f32x16)0.f;
    float mrun = -1e30f, lrun = 0.f;

    auto stage = [&](int k0, int buf) {
        #pragma unroll
        for (int u = 0; u < 4; ++u) {
            int xb = (w * 4 + u) * 1024 + l * 16;
            int rk = xb >> 8, ck = xb & 255;
            gload16(&Kp[(size_t)(k0 + rk) * 128 + ((ck ^ ((rk & 7) << 4)) >> 1)],
                    &Ks[buf][(w * 4 + u) * 512]);
            int rv = xb >> 7, cv = xb & 127;
            gload16(&Vp[(size_t)rv * S_ + k0 + ((cv ^ ((rv & 7) << 4)) >> 1)],
                    &Vs[buf][(w * 4 + u) * 512]);
        }
    };

    stage(0, 0);
    __syncthreads();

    const int NT = S_ / 64;
    for (int kt = 0; kt < NT; ++kt) {
        const int cur = kt & 1;
        if (kt + 1 < NT) stage((kt + 1) * 64, cur ^ 1);

        // --- swapped QK^T: S^T[k][q], A=K, B=Q ---
        f32x16 sacc[2];
        sacc[0] = (f32x16)0.f; sacc[1] = (f32x16)0.f;
        #pragma unroll
        for (int kb = 0; kb < 2; ++kb) {
            #pragma unroll
            for (int ks = 0; ks < 8; ++ks) {
                int row = kb * 32 + lq;
                int byt = row * 256 + ((ks * 32 + hi * 16) ^ ((row & 7) << 4));
                bf16x8 kf = *(const bf16x8*)&Ks[cur][byt >> 1];
                sacc[kb] = __builtin_amdgcn_mfma_f32_32x32x16_bf16(
                    kf, aq[ks], sacc[kb], 0, 0, 0);
            }
        }

        // --- in-register online softmax (lane owns q-row lq; halves split k) ---
        float mx = -1e30f;
        #pragma unroll
        for (int r = 0; r < 16; ++r)
            mx = fmaxf(mx, fmaxf(sacc[0][r], sacc[1][r]));
        mx = fmaxf(mx, __shfl_xor(mx, 32));
        if (__any(mx > mrun + 8.f)) {           // defer-max (T13)
            float mn = fmaxf(mrun, mx);
            float al = __builtin_exp2f(mrun - mn);
            mrun = mn;
            lrun *= al;
            #pragma unroll
            for (int r = 0; r < 16; ++r) {
                int src = (r & 3) + 8 * (r >> 2) + 4 * hi;   // output-row owner
                float alr = __shfl(al, src);
                #pragma unroll
                for (int dt = 0; dt < 4; ++dt) oacc[dt][r] *= alr;
            }
        }
        float ps = 0.f;
        #pragma unroll
        for (int kb = 0; kb < 2; ++kb)
            #pragma unroll
            for (int r = 0; r < 16; ++r) {
                float p = __builtin_exp2f(sacc[kb][r] - mrun);
                sacc[kb][r] = p;
                ps += p;
            }
        ps += __shfl_xor(ps, 32);
        lrun += ps;

        // --- P repack: cvt_pk + permlane32_swap (replaces shfl_xor + selects).
        // swap(a,b): a' = [a.lo | b.lo-from-partner], b' = [a.hi-from-partner | b.hi]
        // -> a' is pa.u[slot0/1] for BOTH halves, b' is pa.u[slot2/3]. ---
        #pragma unroll
        for (int kb = 0; kb < 2; ++kb) {
            u32 wv[8];
            #pragma unroll
            for (int i = 0; i < 8; ++i)
                wv[i] = cvtpk(sacc[kb][2 * i], sacc[kb][2 * i + 1]);
            #pragma unroll
            for (int k2 = 0; k2 < 2; ++k2) {
                u32x2 r0 = __builtin_amdgcn_permlane32_swap(
                    wv[4 * k2 + 0], wv[4 * k2 + 2], false, false);
                u32x2 r1 = __builtin_amdgcn_permlane32_swap(
                    wv[4 * k2 + 1], wv[4 * k2 + 3], false, false);
                union { u32 u[4]; bf16x8 v; } pa;
                pa.u[0] = r0.x; pa.u[1] = r1.x;
                pa.u[2] = r0.y; pa.u[3] = r1.y;
                int kloc = (kb * 2 + k2) * 16 + hi * 8;      // V k-slice base
                #pragma unroll
                for (int dt = 0; dt < 4; ++dt) {
                    int rowv = dt * 32 + lq;
                    int byv  = rowv * 128 + ((kloc * 2) ^ ((rowv & 7) << 4));
                    bf16x8 vf = *(const bf16x8*)&Vs[cur][byv >> 1];
                    oacc[dt] = __builtin_amdgcn_mfma_f32_32x32x16_bf16(
                        pa.v, vf, oacc[dt], 0, 0, 0);
                }
            }
        }
        __syncthreads();
    }

    // epilogue: O[q'][d], q' = (r&3)+8*(r>>2)+4*hi, d = dt*32+lq
    #pragma unroll
    for (int r = 0; r < 16; ++r) {
        int src = (r & 3) + 8 * (r >> 2) + 4 * hi;
        float linv = 1.f / __shfl(lrun, src);
        int s = q0 + src;
        size_t base = ((size_t)bb * S_ + s) * 2048 + h * 128 + lq;
        #pragma unroll
        for (int dt = 0; dt < 4; ++dt)
            AO[base + dt * 32] = f2bf(oacc[dt][r] * linv);
    }
}

// ---------------------------------------------------------------------------
extern "C" void kernel_launch(void* const* d_in, const int* in_sizes, int n_in,
                              void* d_out, int out_size, void* d_ws, size_t ws_size,
                              hipStream_t stream) {
    (void)in_sizes; (void)n_in; (void)out_size; (void)ws_size;
    const float* hid  = (const float*)d_in[0];
    const float* cosb = (const float*)d_in[1];
    const float* sinb = (const float*)d_in[2];
    const float* qw   = (const float*)d_in[3];
    const float* kw   = (const float*)d_in[4];
    const float* vw   = (const float*)d_in[5];
    const float* ow   = (const float*)d_in[6];
    const float* qnw  = (const float*)d_in[7];
    const float* knw  = (const float*)d_in[8];

    u16* ws   = (u16*)d_ws;
    u16* hidB = ws;                         // 8,388,608
    u16* Wc   = ws + 8388608;               // 6,291,456  (qw|kw|vw rows)
    u16* owB  = ws + 14680064;              // 4,194,304
    u16* Qb   = ws + 18874368;              // 8,388,608  [B*H][S][128]
    u16* Kb   = ws + 27262976;              // 2,097,152  [B*KVH][S][128]
    u16* VtB  = ws + 29360128;              // 2,097,152  [B*KVH][128][S]
    u16* AO   = ws + 31457280;              // 8,388,608  [B][S][2048]

    f2b_all<<<dim3(8192, 5), 256, 0, stream>>>(
        hid, hidB, 2097152,
        qw,  Wc,            1048576,
        kw,  Wc + 4194304,  262144,
        vw,  Wc + 5242880,  262144,
        ow,  owB,           1048576);

    gemm_bf16<0><<<dim3(24, 32), 256, 0, stream>>>(hidB, Wc, Qb, Kb, VtB, nullptr);
    norm_rope<<<20480, 256, 0, stream>>>(Qb, Kb, cosb, sinb, qnw, knw);
    attn_mfma<<<512, 256, 0, stream>>>(Qb, Kb, VtB, AO);
    gemm_bf16<1><<<dim3(16, 32), 256, 0, stream>>>(AO, owB, nullptr, nullptr, nullptr,
                                                   (float*)d_out);
}

// Round 7
// 233.580 us; speedup vs baseline: 1.2585x; 1.0146x over previous
//
#include <hip/hip_runtime.h>
#include <hip/hip_bf16.h>
#include <math.h>

#define B_   2
#define S_   2048
#define D_   2048
#define H_   16
#define KVH_ 4
#define HD_  128
#define SCALE 0.08838834764831845f
#define LOG2E 1.44269504088896f
#define EPS_  1e-6f

typedef unsigned short u16;
typedef unsigned int   u32;
typedef __attribute__((ext_vector_type(2)))  unsigned int u32x2;
typedef __attribute__((ext_vector_type(8)))  short bf16x8;   // 8 bf16 (4 VGPRs)
typedef __attribute__((ext_vector_type(4)))  float f32x4;
typedef __attribute__((ext_vector_type(16))) float f32x16;

__device__ __forceinline__ u16 f2bf(float x) {
    union { float f; unsigned int u; } v; v.f = x;
    unsigned int r = v.u + 0x7fffu + ((v.u >> 16) & 1u);
    return (u16)(r >> 16);
}
__device__ __forceinline__ float bf2f(u16 b) {
    union { float f; unsigned int u; } v; v.u = ((unsigned int)b) << 16;
    return v.f;
}
__device__ __forceinline__ u32 cvtpk(float lo, float hi) {
    u32 r;
    asm("v_cvt_pk_bf16_f32 %0, %1, %2" : "=v"(r) : "v"(lo), "v"(hi));
    return r;
}
// async global->LDS, 16B per lane. LDS dest = uniform base + lane*16 (linear);
// swizzle applied on the per-lane GLOBAL source address (rule 21).
__device__ __forceinline__ void gload16(const void* g, void* lds) {
    __builtin_amdgcn_global_load_lds(
        (const __attribute__((address_space(1))) unsigned int*)g,
        (__attribute__((address_space(3))) unsigned int*)lds, 16, 0, 0);
}

// ---------------------------------------------------------------------------
// fp32 -> bf16 convert, all 5 arrays in one launch (blockIdx.y = segment)
// ---------------------------------------------------------------------------
__global__ __launch_bounds__(256) void f2b_all(
    const float* __restrict__ s0, u16* __restrict__ d0, int n0,
    const float* __restrict__ s1, u16* __restrict__ d1, int n1,
    const float* __restrict__ s2, u16* __restrict__ d2, int n2,
    const float* __restrict__ s3, u16* __restrict__ d3, int n3,
    const float* __restrict__ s4, u16* __restrict__ d4, int n4)
{
    const float* s; u16* d; int n;
    switch (blockIdx.y) {
        case 0: s = s0; d = d0; n = n0; break;
        case 1: s = s1; d = d1; n = n1; break;
        case 2: s = s2; d = d2; n = n2; break;
        case 3: s = s3; d = d3; n = n3; break;
        default: s = s4; d = d4; n = n4; break;
    }
    int i = blockIdx.x * 256 + threadIdx.x;
    if (i >= n) return;
    float4 v = ((const float4*)s)[i];
    ushort4 o = make_ushort4(f2bf(v.x), f2bf(v.y), f2bf(v.z), f2bf(v.w));
    ((ushort4*)d)[i] = o;
}

// ---------------------------------------------------------------------------
// bf16 MFMA GEMM, m97 structure: 128x128 tile, BK=64, 4 waves (2x2 of 64x64),
// global_load_lds w=16 with pre-swizzled source; XOR-swizzled ds_read_b128.
// MODE 0: QKV projection with head-major scatter epilogue (V transposed).
// MODE 1: O projection, fp32 output.
// ---------------------------------------------------------------------------
template<int MODE>
__global__ __launch_bounds__(256) void gemm_bf16(
    const u16* __restrict__ A,    // [4096][2048] bf16
    const u16* __restrict__ Bw,   // [N][2048] bf16 (rows = output cols)
    u16* __restrict__ Qo, u16* __restrict__ Ko, u16* __restrict__ Vt,
    float* __restrict__ Co)
{
    __shared__ u16 As[128 * 64];
    __shared__ u16 Bs[128 * 64];

    const int t  = threadIdx.x;
    const int w  = t >> 6, l = t & 63;
    const int wm = w >> 1, wn = w & 1;
    const int lr = l & 15, lh = l >> 4;
    const int n0 = blockIdx.x * 128;
    const int m0 = blockIdx.y * 128;

    f32x4 acc[4][4];
    #pragma unroll
    for (int i = 0; i < 4; ++i)
        #pragma unroll
        for (int j = 0; j < 4; ++j)
            acc[i][j] = (f32x4)0.f;

    const int x = (w * 4) * 1024 + l * 16;
    for (int k0 = 0; k0 < 2048; k0 += 64) {
        #pragma unroll
        for (int u = 0; u < 4; ++u) {
            int xb = x + u * 1024;
            int r  = xb >> 7;
            int c  = xb & 127;
            int cs = c ^ ((r & 7) << 4);
            gload16(&A[(size_t)(m0 + r) * 2048 + k0 + (cs >> 1)], &As[(w * 4 + u) * 512]);
            gload16(&Bw[(size_t)(n0 + r) * 2048 + k0 + (cs >> 1)], &Bs[(w * 4 + u) * 512]);
        }
        __syncthreads();
        #pragma unroll
        for (int kc = 0; kc < 2; ++kc) {
            bf16x8 af[4], bfr[4];
            #pragma unroll
            for (int i = 0; i < 4; ++i) {
                int row = wm * 64 + i * 16 + lr;
                int byt = row * 128 + ((kc * 64 + lh * 16) ^ ((row & 7) << 4));
                af[i] = *(const bf16x8*)&As[byt >> 1];
                int rob = wn * 64 + i * 16 + lr;
                int byb = rob * 128 + ((kc * 64 + lh * 16) ^ ((rob & 7) << 4));
                bfr[i] = *(const bf16x8*)&Bs[byb >> 1];
            }
            #pragma unroll
            for (int i = 0; i < 4; ++i)
                #pragma unroll
                for (int j = 0; j < 4; ++j)
                    acc[i][j] = __builtin_amdgcn_mfma_f32_16x16x32_bf16(
                        af[i], bfr[j], acc[i][j], 0, 0, 0);
        }
        __syncthreads();
    }

    // epilogue.  C/D layout: row = (l>>4)*4 + reg, col = l&15
    #pragma unroll
    for (int i = 0; i < 4; ++i) {
        #pragma unroll
        for (int j = 0; j < 4; ++j) {
            int col = n0 + wn * 64 + j * 16 + lr;
            #pragma unroll
            for (int r = 0; r < 4; ++r) {
                int m = m0 + wm * 64 + i * 16 + lh * 4 + r;
                float v = acc[i][j][r];
                if (MODE == 0) {
                    int bb = m >> 11, s = m & 2047;
                    if (col < 2048) {
                        int hh = col >> 7, d = col & 127;
                        Qo[((size_t)(bb * H_ + hh) * S_ + s) * HD_ + d] = f2bf(v);
                    } else if (col < 2560) {
                        int c2 = col - 2048; int hh = c2 >> 7, d = c2 & 127;
                        Ko[((size_t)(bb * KVH_ + hh) * S_ + s) * HD_ + d] = f2bf(v);
                    } else {
                        int c2 = col - 2560; int hh = c2 >> 7, d = c2 & 127;
                        Vt[((size_t)(bb * KVH_ + hh) * HD_ + d) * S_ + s] = f2bf(v);
                    }
                } else {
                    Co[(size_t)m * 2048 + col] = v;
                }
            }
        }
    }
}

// ---------------------------------------------------------------------------
// RMSNorm + RoPE in place (bf16).  One wave per 128-elem row.
// Q gets SCALE*LOG2E folded (attention uses exp2 directly).
// ---------------------------------------------------------------------------
__global__ __launch_bounds__(256) void norm_rope(
    u16* __restrict__ Qb, u16* __restrict__ Kb,
    const float* __restrict__ cosb, const float* __restrict__ sinb,
    const float* __restrict__ qnw, const float* __restrict__ knw)
{
    const int rid = blockIdx.x * 4 + (threadIdx.x >> 6);
    const int l   = threadIdx.x & 63;
    u16* row; const float* wn; int s; float sc;
    if (rid < B_ * H_ * S_) {
        row = Qb + (size_t)rid * HD_; wn = qnw; s = rid & (S_ - 1); sc = SCALE * LOG2E;
    } else {
        int r2 = rid - B_ * H_ * S_;
        row = Kb + (size_t)r2 * HD_; wn = knw; s = r2 & (S_ - 1); sc = 1.f;
    }
    unsigned int u = *(const unsigned int*)&row[2 * l];
    float x0 = bf2f((u16)(u & 0xffff)), x1 = bf2f((u16)(u >> 16));
    float ss = x0 * x0 + x1 * x1;
    #pragma unroll
    for (int off = 1; off < 64; off <<= 1) ss += __shfl_xor(ss, off);
    float rr = rsqrtf(ss * (1.f / 128.f) + 1e-6f);
    float n0 = x0 * rr * wn[2 * l];
    float n1 = x1 * rr * wn[2 * l + 1];
    float p0 = __shfl_xor(n0, 32);
    float p1 = __shfl_xor(n1, 32);
    float sg = (l < 32) ? -1.f : 1.f;
    const float* cp = cosb + s * HD_;
    const float* sp = sinb + s * HD_;
    float o0 = (n0 * cp[2 * l]     + sg * p0 * sp[2 * l])     * sc;
    float o1 = (n1 * cp[2 * l + 1] + sg * p1 * sp[2 * l + 1]) * sc;
    unsigned int o = (unsigned int)f2bf(o0) | ((unsigned int)f2bf(o1) << 16);
    *(unsigned int*)&row[2 * l] = o;
}

// ---------------------------------------------------------------------------
// Flash attention (m214 structure + T15-lite deferred-PV pipeline):
// 4 warps x 32 q-rows, KVBLK=64, swapped QK^T, in-register softmax w/
// defer-max, cvt_pk + permlane32_swap P repack held in pan[] one iteration;
// per iter: QK(k) -> PV(k-1) [MFMA, overlaps max-reduce VALU] -> rescale ->
// exp(k) -> repack(k).  K double-buffered, V TRIPLE-buffered (PV reads V one
// tile behind the prefetch).  LDS = 80 KB = 2 blocks/CU exactly.
// ---------------------------------------------------------------------------
__global__ __launch_bounds__(256, 2) void attn_mfma(
    const u16* __restrict__ Q,    // [B*H][S][128], SCALE*LOG2E pre-folded
    const u16* __restrict__ K,    // [B*KVH][S][128]
    const u16* __restrict__ Vt,   // [B*KVH][128][S]
    u16* __restrict__ AO)         // [B][S][2048]
{
    __shared__ u16 Ks[2][64 * 128];     // rows 256B, XOR-swizzled
    __shared__ u16 Vs[3][128 * 64];     // rows 128B, XOR-swizzled (tri-buffer)

    const int t  = threadIdx.x, w = t >> 6, l = t & 63;
    const int lq = l & 31, hi = l >> 5;
    // XCD-chunked swizzle: 512 blocks, 64/XCD = one (b,kvh) per XCD
    const int id = (blockIdx.x & 7) * 64 + (blockIdx.x >> 3);
    const int qx = id & 15, bh = id >> 4;
    const int bb = bh >> 4, h = bh & 15;
    const int kv = bb * KVH_ + (h >> 2);
    const int q0 = qx * 128 + w * 32;

    const u16* Qp = Q + ((size_t)bh * S_ + q0) * HD_;
    const u16* Kp = K + (size_t)kv * S_ * HD_;
    const u16* Vp = Vt + (size_t)kv * HD_ * S_;

    // Q as B-operand fragments: col=q=lane&31, k-elem j -> d = ks*16 + hi*8 + j
    bf16x8 aq[8];
    #pragma unroll
    for (int ks = 0; ks < 8; ++ks)
        aq[ks] = *(const bf16x8*)&Qp[(size_t)lq * 128 + ks * 16 + hi * 8];

    f32x16 oacc[4];
    #pragma unroll
    for (int dt = 0; dt < 4; ++dt) oacc[dt] = (f32x16)0.f;
    float mrun = -1e30f, lrun = 0.f;
    u32 pan[16];                        // packed P of previous tile (4 groups x 4)

    auto stage = [&](int k0, int kbuf, int vbuf) {
        #pragma unroll
        for (int u = 0; u < 4; ++u) {
            int xb = (w * 4 + u) * 1024 + l * 16;
            int rk = xb >> 8, ck = xb & 255;
            gload16(&Kp[(size_t)(k0 + rk) * 128 + ((ck ^ ((rk & 7) << 4)) >> 1)],
                    &Ks[kbuf][(w * 4 + u) * 512]);
            int rv = xb >> 7, cv = xb & 127;
            gload16(&Vp[(size_t)rv * S_ + k0 + ((cv ^ ((rv & 7) << 4)) >> 1)],
                    &Vs[vbuf][(w * 4 + u) * 512]);
        }
    };

    stage(0, 0, 0);
    __syncthreads();

    const int NT = S_ / 64;
    for (int kt = 0; kt < NT; ++kt) {
        const int kcur = kt & 1;
        if (kt + 1 < NT) stage((kt + 1) * 64, (kt + 1) & 1, (kt + 1) % 3);

        // --- swapped QK^T: S^T[k][q], A=K, B=Q ---
        f32x16 sacc[2];
        sacc[0] = (f32x16)0.f; sacc[1] = (f32x16)0.f;
        #pragma unroll
        for (int kb = 0; kb < 2; ++kb) {
            #pragma unroll
            for (int ks = 0; ks < 8; ++ks) {
                int row = kb * 32 + lq;
                int byt = row * 256 + ((ks * 32 + hi * 16) ^ ((row & 7) << 4));
                bf16x8 kf = *(const bf16x8*)&Ks[kcur][byt >> 1];
                sacc[kb] = __builtin_amdgcn_mfma_f32_32x32x16_bf16(
                    kf, aq[ks], sacc[kb], 0, 0, 0);
            }
        }

        // --- max-reduce(k) (VALU) ∥ PV(k-1) (MFMA, independent) ---
        float mx = -1e30f;
        #pragma unroll
        for (int r = 0; r < 16; ++r)
            mx = fmaxf(mx, fmaxf(sacc[0][r], sacc[1][r]));
        mx = fmaxf(mx, __shfl_xor(mx, 32));

        if (kt > 0) {
            const int vprev = (kt + 2) % 3;     // == (kt-1) % 3
            #pragma unroll
            for (int g = 0; g < 4; ++g) {
                union { u32 u[4]; bf16x8 v; } pa;
                pa.u[0] = pan[g * 4 + 0]; pa.u[1] = pan[g * 4 + 1];
                pa.u[2] = pan[g * 4 + 2]; pa.u[3] = pan[g * 4 + 3];
                int kloc = g * 16 + hi * 8;
                #pragma unroll
                for (int dt = 0; dt < 4; ++dt) {
                    int rowv = dt * 32 + lq;
                    int byv  = rowv * 128 + ((kloc * 2) ^ ((rowv & 7) << 4));
                    bf16x8 vf = *(const bf16x8*)&Vs[vprev][byv >> 1];
                    oacc[dt] = __builtin_amdgcn_mfma_f32_32x32x16_bf16(
                        pa.v, vf, oacc[dt], 0, 0, 0);
                }
            }
        }

        // --- rescale (after PV(k-1) has landed on oacc) ---
        if (__any(mx > mrun + 8.f)) {           // defer-max (T13)
            float mn = fmaxf(mrun, mx);
            float al = __builtin_exp2f(mrun - mn);
            mrun = mn;
            lrun *= al;
            #pragma unroll
            for (int r = 0; r < 16; ++r) {
                int src = (r & 3) + 8 * (r >> 2) + 4 * hi;   // output-row owner
                float alr = __shfl(al, src);
                #pragma unroll
                for (int dt = 0; dt < 4; ++dt) oacc[dt][r] *= alr;
            }
        }

        // --- exp2(k), row sums ---
        float ps = 0.f;
        #pragma unroll
        for (int kb = 0; kb < 2; ++kb)
            #pragma unroll
            for (int r = 0; r < 16; ++r) {
                float p = __builtin_exp2f(sacc[kb][r] - mrun);
                sacc[kb][r] = p;
                ps += p;
            }
        ps += __shfl_xor(ps, 32);
        lrun += ps;

        // --- P repack: cvt_pk + permlane32_swap -> pan (consumed next iter) ---
        #pragma unroll
        for (int kb = 0; kb < 2; ++kb) {
            u32 wv[8];
            #pragma unroll
            for (int i = 0; i < 8; ++i)
                wv[i] = cvtpk(sacc[kb][2 * i], sacc[kb][2 * i + 1]);
            #pragma unroll
            for (int k2 = 0; k2 < 2; ++k2) {
                u32x2 r0 = __builtin_amdgcn_permlane32_swap(
                    wv[4 * k2 + 0], wv[4 * k2 + 2], false, false);
                u32x2 r1 = __builtin_amdgcn_permlane32_swap(
                    wv[4 * k2 + 1], wv[4 * k2 + 3], false, false);
                int g = kb * 2 + k2;
                pan[g * 4 + 0] = r0.x; pan[g * 4 + 1] = r1.x;
                pan[g * 4 + 2] = r0.y; pan[g * 4 + 3] = r1.y;
            }
        }
        __syncthreads();
    }

    // --- final PV(NT-1) ---
    {
        const int vprev = (NT - 1) % 3;
        #pragma unroll
        for (int g = 0; g < 4; ++g) {
            union { u32 u[4]; bf16x8 v; } pa;
            pa.u[0] = pan[g * 4 + 0]; pa.u[1] = pan[g * 4 + 1];
            pa.u[2] = pan[g * 4 + 2]; pa.u[3] = pan[g * 4 + 3];
            int kloc = g * 16 + hi * 8;
            #pragma unroll
            for (int dt = 0; dt < 4; ++dt) {
                int rowv = dt * 32 + lq;
                int byv  = rowv * 128 + ((kloc * 2) ^ ((rowv & 7) << 4));
                bf16x8 vf = *(const bf16x8*)&Vs[vprev][byv >> 1];
                oacc[dt] = __builtin_amdgcn_mfma_f32_32x32x16_bf16(
                    pa.v, vf, oacc[dt], 0, 0, 0);
            }
        }
    }

    // epilogue: O[q'][d], q' = (r&3)+8*(r>>2)+4*hi, d = dt*32+lq
    #pragma unroll
    for (int r = 0; r < 16; ++r) {
        int src = (r & 3) + 8 * (r >> 2) + 4 * hi;
        float linv = 1.f / __shfl(lrun, src);
        int s = q0 + src;
        size_t base = ((size_t)bb * S_ + s) * 2048 + h * 128 + lq;
        #pragma unroll
        for (int dt = 0; dt < 4; ++dt)
            AO[base + dt * 32] = f2bf(oacc[dt][r] * linv);
    }
}

// ---------------------------------------------------------------------------
extern "C" void kernel_launch(void* const* d_in, const int* in_sizes, int n_in,
                              void* d_out, int out_size, void* d_ws, size_t ws_size,
                              hipStream_t stream) {
    (void)in_sizes; (void)n_in; (void)out_size; (void)ws_size;
    const float* hid  = (const float*)d_in[0];
    const float* cosb = (const float*)d_in[1];
    const float* sinb = (const float*)d_in[2];
    const float* qw   = (const float*)d_in[3];
    const float* kw   = (const float*)d_in[4];
    const float* vw   = (const float*)d_in[5];
    const float* ow   = (const float*)d_in[6];
    const float* qnw  = (const float*)d_in[7];
    const float* knw  = (const float*)d_in[8];

    u16* ws   = (u16*)d_ws;
    u16* hidB = ws;                         // 8,388,608
    u16* Wc   = ws + 8388608;               // 6,291,456  (qw|kw|vw rows)
    u16* owB  = ws + 14680064;              // 4,194,304
    u16* Qb   = ws + 18874368;              // 8,388,608  [B*H][S][128]
    u16* Kb   = ws + 27262976;              // 2,097,152  [B*KVH][S][128]
    u16* VtB  = ws + 29360128;              // 2,097,152  [B*KVH][128][S]
    u16* AO   = ws + 31457280;              // 8,388,608  [B][S][2048]

    f2b_all<<<dim3(8192, 5), 256, 0, stream>>>(
        hid, hidB, 2097152,
        qw,  Wc,            1048576,
        kw,  Wc + 4194304,  262144,
        vw,  Wc + 5242880,  262144,
        ow,  owB,           1048576);

    gemm_bf16<0><<<dim3(24, 32), 256, 0, stream>>>(hidB, Wc, Qb, Kb, VtB, nullptr);
    norm_rope<<<20480, 256, 0, stream>>>(Qb, Kb, cosb, sinb, qnw, knw);
    attn_mfma<<<512, 256, 0, stream>>>(Qb, Kb, VtB, AO);
    gemm_bf16<1><<<dim3(16, 32), 256, 0, stream>>>(AO, owB, nullptr, nullptr, nullptr,
                                                   (float*)d_out);
}

// Round 8
// 231.504 us; speedup vs baseline: 1.2698x; 1.0090x over previous
//
#include <hip/hip_runtime.h>
#include <hip/hip_bf16.h>
#include <math.h>

#define B_   2
#define S_   2048
#define D_   2048
#define H_   16
#define KVH_ 4
#define HD_  128
#define SCALE 0.08838834764831845f
#define LOG2E 1.44269504088896f
#define QSC_  (SCALE * LOG2E)
#define EPS_  1e-6f

typedef unsigned short u16;
typedef unsigned int   u32;
typedef __attribute__((ext_vector_type(2)))  unsigned int u32x2;
typedef __attribute__((ext_vector_type(2)))  float f32x2;
typedef __attribute__((ext_vector_type(8)))  short bf16x8;   // 8 bf16 (4 VGPRs)
typedef __attribute__((ext_vector_type(4)))  float f32x4;
typedef __attribute__((ext_vector_type(16))) float f32x16;

__device__ __forceinline__ u16 f2bf(float x) {
    union { float f; unsigned int u; } v; v.f = x;
    unsigned int r = v.u + 0x7fffu + ((v.u >> 16) & 1u);
    return (u16)(r >> 16);
}
__device__ __forceinline__ float bf2f(u16 b) {
    union { float f; unsigned int u; } v; v.u = ((unsigned int)b) << 16;
    return v.f;
}
__device__ __forceinline__ u32 cvtpk(float lo, float hi) {
    u32 r;
    asm("v_cvt_pk_bf16_f32 %0, %1, %2" : "=v"(r) : "v"(lo), "v"(hi));
    return r;
}
// packed fp32 (CDNA gfx90a+) and max3 helpers
__device__ __forceinline__ f32x2 pk_sub(f32x2 a, f32x2 b) {   // a - b
    f32x2 r;
    asm("v_pk_add_f32 %0, %1, %2 neg_lo:[0,1] neg_hi:[0,1]" : "=v"(r) : "v"(a), "v"(b));
    return r;
}
__device__ __forceinline__ f32x2 pk_add(f32x2 a, f32x2 b) {
    f32x2 r; asm("v_pk_add_f32 %0, %1, %2" : "=v"(r) : "v"(a), "v"(b)); return r;
}
__device__ __forceinline__ float max3f(float a, float b, float c) {
    float r; asm("v_max3_f32 %0, %1, %2, %3" : "=v"(r) : "v"(a), "v"(b), "v"(c)); return r;
}
// async global->LDS, 16B per lane. LDS dest = uniform base + lane*16 (linear);
// swizzle applied on the per-lane GLOBAL source address (rule 21).
__device__ __forceinline__ void gload16(const void* g, void* lds) {
    __builtin_amdgcn_global_load_lds(
        (const __attribute__((address_space(1))) unsigned int*)g,
        (__attribute__((address_space(3))) unsigned int*)lds, 16, 0, 0);
}

// ---------------------------------------------------------------------------
// fp32 -> bf16 convert, all 5 arrays in one launch (blockIdx.y = segment)
// ---------------------------------------------------------------------------
__global__ __launch_bounds__(256) void f2b_all(
    const float* __restrict__ s0, u16* __restrict__ d0, int n0,
    const float* __restrict__ s1, u16* __restrict__ d1, int n1,
    const float* __restrict__ s2, u16* __restrict__ d2, int n2,
    const float* __restrict__ s3, u16* __restrict__ d3, int n3,
    const float* __restrict__ s4, u16* __restrict__ d4, int n4)
{
    const float* s; u16* d; int n;
    switch (blockIdx.y) {
        case 0: s = s0; d = d0; n = n0; break;
        case 1: s = s1; d = d1; n = n1; break;
        case 2: s = s2; d = d2; n = n2; break;
        case 3: s = s3; d = d3; n = n3; break;
        default: s = s4; d = d4; n = n4; break;
    }
    int i = blockIdx.x * 256 + threadIdx.x;
    if (i >= n) return;
    float4 v = ((const float4*)s)[i];
    ushort4 o = make_ushort4(f2bf(v.x), f2bf(v.y), f2bf(v.z), f2bf(v.w));
    ((ushort4*)d)[i] = o;
}

// ---------------------------------------------------------------------------
// bf16 MFMA GEMM, m97 structure: 128x128 tile, BK=64, 4 waves (2x2 of 64x64),
// global_load_lds w=16 with pre-swizzled source; XOR-swizzled ds_read_b128.
// MODE 0: QKV projection with head-major scatter epilogue (V transposed).
// MODE 1: O projection, fp32 output.
// ---------------------------------------------------------------------------
template<int MODE>
__global__ __launch_bounds__(256) void gemm_bf16(
    const u16* __restrict__ A,    // [4096][2048] bf16
    const u16* __restrict__ Bw,   // [N][2048] bf16 (rows = output cols)
    u16* __restrict__ Qo, u16* __restrict__ Ko, u16* __restrict__ Vt,
    float* __restrict__ Co)
{
    __shared__ u16 As[128 * 64];
    __shared__ u16 Bs[128 * 64];

    const int t  = threadIdx.x;
    const int w  = t >> 6, l = t & 63;
    const int wm = w >> 1, wn = w & 1;
    const int lr = l & 15, lh = l >> 4;
    const int n0 = blockIdx.x * 128;
    const int m0 = blockIdx.y * 128;

    f32x4 acc[4][4];
    #pragma unroll
    for (int i = 0; i < 4; ++i)
        #pragma unroll
        for (int j = 0; j < 4; ++j)
            acc[i][j] = (f32x4)0.f;

    const int x = (w * 4) * 1024 + l * 16;
    for (int k0 = 0; k0 < 2048; k0 += 64) {
        #pragma unroll
        for (int u = 0; u < 4; ++u) {
            int xb = x + u * 1024;
            int r  = xb >> 7;
            int c  = xb & 127;
            int cs = c ^ ((r & 7) << 4);
            gload16(&A[(size_t)(m0 + r) * 2048 + k0 + (cs >> 1)], &As[(w * 4 + u) * 512]);
            gload16(&Bw[(size_t)(n0 + r) * 2048 + k0 + (cs >> 1)], &Bs[(w * 4 + u) * 512]);
        }
        __syncthreads();
        #pragma unroll
        for (int kc = 0; kc < 2; ++kc) {
            bf16x8 af[4], bfr[4];
            #pragma unroll
            for (int i = 0; i < 4; ++i) {
                int row = wm * 64 + i * 16 + lr;
                int byt = row * 128 + ((kc * 64 + lh * 16) ^ ((row & 7) << 4));
                af[i] = *(const bf16x8*)&As[byt >> 1];
                int rob = wn * 64 + i * 16 + lr;
                int byb = rob * 128 + ((kc * 64 + lh * 16) ^ ((rob & 7) << 4));
                bfr[i] = *(const bf16x8*)&Bs[byb >> 1];
            }
            #pragma unroll
            for (int i = 0; i < 4; ++i)
                #pragma unroll
                for (int j = 0; j < 4; ++j)
                    acc[i][j] = __builtin_amdgcn_mfma_f32_16x16x32_bf16(
                        af[i], bfr[j], acc[i][j], 0, 0, 0);
        }
        __syncthreads();
    }

    // epilogue.  C/D layout: row = (l>>4)*4 + reg, col = l&15
    #pragma unroll
    for (int i = 0; i < 4; ++i) {
        #pragma unroll
        for (int j = 0; j < 4; ++j) {
            int col = n0 + wn * 64 + j * 16 + lr;
            #pragma unroll
            for (int r = 0; r < 4; ++r) {
                int m = m0 + wm * 64 + i * 16 + lh * 4 + r;
                float v = acc[i][j][r];
                if (MODE == 0) {
                    int bb = m >> 11, s = m & 2047;
                    if (col < 2048) {
                        int hh = col >> 7, d = col & 127;
                        Qo[((size_t)(bb * H_ + hh) * S_ + s) * HD_ + d] = f2bf(v);
                    } else if (col < 2560) {
                        int c2 = col - 2048; int hh = c2 >> 7, d = c2 & 127;
                        Ko[((size_t)(bb * KVH_ + hh) * S_ + s) * HD_ + d] = f2bf(v);
                    } else {
                        int c2 = col - 2560; int hh = c2 >> 7, d = c2 & 127;
                        Vt[((size_t)(bb * KVH_ + hh) * HD_ + d) * S_ + s] = f2bf(v);
                    }
                } else {
                    Co[(size_t)m * 2048 + col] = v;
                }
            }
        }
    }
}

// ---------------------------------------------------------------------------
// RMSNorm + RoPE in place (bf16) -- K ONLY (Q is fused into attention).
// One wave per 128-elem row.
// ---------------------------------------------------------------------------
__global__ __launch_bounds__(256) void norm_rope_k(
    u16* __restrict__ Kb,
    const float* __restrict__ cosb, const float* __restrict__ sinb,
    const float* __restrict__ knw)
{
    const int rid = blockIdx.x * 4 + (threadIdx.x >> 6);
    const int l   = threadIdx.x & 63;
    u16* row = Kb + (size_t)rid * HD_;
    const int s  = rid & (S_ - 1);
    unsigned int u = *(const unsigned int*)&row[2 * l];
    float x0 = bf2f((u16)(u & 0xffff)), x1 = bf2f((u16)(u >> 16));
    float ss = x0 * x0 + x1 * x1;
    #pragma unroll
    for (int off = 1; off < 64; off <<= 1) ss += __shfl_xor(ss, off);
    float rr = rsqrtf(ss * (1.f / 128.f) + EPS_);
    float n0 = x0 * rr * knw[2 * l];
    float n1 = x1 * rr * knw[2 * l + 1];
    float p0 = __shfl_xor(n0, 32);
    float p1 = __shfl_xor(n1, 32);
    float sg = (l < 32) ? -1.f : 1.f;
    const float* cp = cosb + s * HD_;
    const float* sp = sinb + s * HD_;
    float o0 = n0 * cp[2 * l]     + sg * p0 * sp[2 * l];
    float o1 = n1 * cp[2 * l + 1] + sg * p1 * sp[2 * l + 1];
    unsigned int o = (unsigned int)f2bf(o0) | ((unsigned int)f2bf(o1) << 16);
    *(unsigned int*)&row[2 * l] = o;
}

// ---------------------------------------------------------------------------
// Flash attention (m214 structure + deferred-PV pipeline + fused Q-norm/RoPE
// + packed-fp32 softmax):
// 4 warps x 32 q-rows, KVBLK=64, swapped QK^T, in-register softmax with
// defer-max, cvt_pk + permlane32_swap P repack held one iteration (PV(k-1)
// overlaps max-reduce(k)).  K dbuf + V tri-buf, 80 KB LDS = 2 blocks/CU.
// Q RMSNorm+RoPE computed in-register at load (rope pair d/d+64 lane-local).
// ---------------------------------------------------------------------------
__global__ __launch_bounds__(256, 2) void attn_mfma(
    const u16* __restrict__ Q,    // [B*H][S][128] RAW (un-normed) bf16
    const u16* __restrict__ K,    // [B*KVH][S][128] normed+roped
    const u16* __restrict__ Vt,   // [B*KVH][128][S]
    u16* __restrict__ AO,         // [B][S][2048]
    const float* __restrict__ cosb, const float* __restrict__ sinb,
    const float* __restrict__ qnw)
{
    __shared__ u16 Ks[2][64 * 128];     // rows 256B, XOR-swizzled
    __shared__ u16 Vs[3][128 * 64];     // rows 128B, XOR-swizzled (tri-buffer)

    const int t  = threadIdx.x, w = t >> 6, l = t & 63;
    const int lq = l & 31, hi = l >> 5;
    // XCD-chunked swizzle: 512 blocks, 64/XCD = one (b,kvh) per XCD
    const int id = (blockIdx.x & 7) * 64 + (blockIdx.x >> 3);
    const int qx = id & 15, bh = id >> 4;
    const int bb = bh >> 4, h = bh & 15;
    const int kv = bb * KVH_ + (h >> 2);
    const int q0 = qx * 128 + w * 32;

    const u16* Qp = Q + ((size_t)bh * S_ + q0) * HD_;
    const u16* Kp = K + (size_t)kv * S_ * HD_;
    const u16* Vp = Vt + (size_t)kv * HD_ * S_;

    // --- fused Q load + RMSNorm + RoPE + scale (lane owns row q0+lq) ---
    // B-frag: col=q=lq, k-elem j -> d = ks*16 + hi*8 + j.  Pair (d, d+64)
    // lives in frags (ks, ks+4) of the SAME lane -> rope is lane-local.
    bf16x8 aq[8];
    {
        bf16x8 raw[8];
        #pragma unroll
        for (int ks = 0; ks < 8; ++ks)
            raw[ks] = *(const bf16x8*)&Qp[(size_t)lq * 128 + ks * 16 + hi * 8];
        float ssq = 0.f;
        #pragma unroll
        for (int ks = 0; ks < 8; ++ks)
            #pragma unroll
            for (int e = 0; e < 8; ++e) {
                float xv = bf2f((u16)raw[ks][e]); ssq += xv * xv;
            }
        ssq += __shfl_xor(ssq, 32);
        float rr = rsqrtf(ssq * (1.f / 128.f) + EPS_);
        const int srow = q0 + lq;
        const float* cp = cosb + srow * HD_;
        const float* sp = sinb + srow * HD_;
        #pragma unroll
        for (int ks = 0; ks < 4; ++ks) {
            const int dlo = ks * 16 + hi * 8;
            const int dhi = dlo + 64;
            float olo[8], ohi[8];
            #pragma unroll
            for (int e = 0; e < 8; ++e) {
                float nlo = bf2f((u16)raw[ks][e])     * rr * qnw[dlo + e];
                float nhi = bf2f((u16)raw[ks + 4][e]) * rr * qnw[dhi + e];
                float c0 = cp[dlo + e] * QSC_, s0 = sp[dlo + e] * QSC_;
                float c1 = cp[dhi + e] * QSC_, s1 = sp[dhi + e] * QSC_;
                olo[e] = nlo * c0 - nhi * s0;
                ohi[e] = nhi * c1 + nlo * s1;
            }
            union { u32 u[4]; bf16x8 v; } plo, phi;
            #pragma unroll
            for (int e2 = 0; e2 < 4; ++e2) {
                plo.u[e2] = cvtpk(olo[2 * e2], olo[2 * e2 + 1]);
                phi.u[e2] = cvtpk(ohi[2 * e2], ohi[2 * e2 + 1]);
            }
            aq[ks]     = plo.v;
            aq[ks + 4] = phi.v;
        }
    }

    f32x16 oacc[4];
    #pragma unroll
    for (int dt = 0; dt < 4; ++dt) oacc[dt] = (f32x16)0.f;
    float mrun = -1e30f, lrun = 0.f;
    u32 pan[16];                        // packed P of previous tile (4 groups x 4)

    auto stage = [&](int k0, int kbuf, int vbuf) {
        #pragma unroll
        for (int u = 0; u < 4; ++u) {
            int xb = (w * 4 + u) * 1024 + l * 16;
            int rk = xb >> 8, ck = xb & 255;
            gload16(&Kp[(size_t)(k0 + rk) * 128 + ((ck ^ ((rk & 7) << 4)) >> 1)],
                    &Ks[kbuf][(w * 4 + u) * 512]);
            int rv = xb >> 7, cv = xb & 127;
            gload16(&Vp[(size_t)rv * S_ + k0 + ((cv ^ ((rv & 7) << 4)) >> 1)],
                    &Vs[vbuf][(w * 4 + u) * 512]);
        }
    };

    stage(0, 0, 0);
    __syncthreads();

    const int NT = S_ / 64;
    for (int kt = 0; kt < NT; ++kt) {
        const int kcur = kt & 1;
        if (kt + 1 < NT) stage((kt + 1) * 64, (kt + 1) & 1, (kt + 1) % 3);

        // --- swapped QK^T: S^T[k][q], A=K, B=Q ---
        f32x16 sacc[2];
        sacc[0] = (f32x16)0.f; sacc[1] = (f32x16)0.f;
        #pragma unroll
        for (int kb = 0; kb < 2; ++kb) {
            #pragma unroll
            for (int ks = 0; ks < 8; ++ks) {
                int row = kb * 32 + lq;
                int byt = row * 256 + ((ks * 32 + hi * 16) ^ ((row & 7) << 4));
                bf16x8 kf = *(const bf16x8*)&Ks[kcur][byt >> 1];
                sacc[kb] = __builtin_amdgcn_mfma_f32_32x32x16_bf16(
                    kf, aq[ks], sacc[kb], 0, 0, 0);
            }
        }

        // --- max-reduce(k) via v_max3 (VALU) ∥ PV(k-1) (MFMA, independent) ---
        float mxa = max3f(sacc[0][0], sacc[0][1], sacc[0][2]);
        float mxb = max3f(sacc[1][0], sacc[1][1], sacc[1][2]);
        #pragma unroll
        for (int r = 3; r < 15; r += 2) {
            mxa = max3f(mxa, sacc[0][r], sacc[0][r + 1]);
            mxb = max3f(mxb, sacc[1][r], sacc[1][r + 1]);
        }
        float mx = max3f(fmaxf(mxa, sacc[0][15]), mxb, sacc[1][15]);
        mx = fmaxf(mx, __shfl_xor(mx, 32));

        if (kt > 0) {
            const int vprev = (kt + 2) % 3;     // == (kt-1) % 3
            #pragma unroll
            for (int g = 0; g < 4; ++g) {
                union { u32 u[4]; bf16x8 v; } pa;
                pa.u[0] = pan[g * 4 + 0]; pa.u[1] = pan[g * 4 + 1];
                pa.u[2] = pan[g * 4 + 2]; pa.u[3] = pan[g * 4 + 3];
                int kloc = g * 16 + hi * 8;
                #pragma unroll
                for (int dt = 0; dt < 4; ++dt) {
                    int rowv = dt * 32 + lq;
                    int byv  = rowv * 128 + ((kloc * 2) ^ ((rowv & 7) << 4));
                    bf16x8 vf = *(const bf16x8*)&Vs[vprev][byv >> 1];
                    oacc[dt] = __builtin_amdgcn_mfma_f32_32x32x16_bf16(
                        pa.v, vf, oacc[dt], 0, 0, 0);
                }
            }
        }

        // --- rescale (after PV(k-1) has landed on oacc) ---
        if (__any(mx > mrun + 8.f)) {           // defer-max (T13)
            float mn = fmaxf(mrun, mx);
            float al = __builtin_exp2f(mrun - mn);
            mrun = mn;
            lrun *= al;
            #pragma unroll
            for (int r = 0; r < 16; ++r) {
                int src = (r & 3) + 8 * (r >> 2) + 4 * hi;   // output-row owner
                float alr = __shfl(al, src);
                #pragma unroll
                for (int dt = 0; dt < 4; ++dt) oacc[dt][r] *= alr;
            }
        }

        // --- exp2(k) with packed sub, packed row sums ---
        f32x2 mr2; mr2.x = mrun; mr2.y = mrun;
        f32x2 ps2; ps2.x = 0.f; ps2.y = 0.f;
        #pragma unroll
        for (int kb = 0; kb < 2; ++kb) {
            f32x2* s2 = (f32x2*)&sacc[kb];
            #pragma unroll
            for (int i = 0; i < 8; ++i) {
                f32x2 dv = pk_sub(s2[i], mr2);
                dv.x = __builtin_exp2f(dv.x);
                dv.y = __builtin_exp2f(dv.y);
                s2[i] = dv;
                ps2 = pk_add(ps2, dv);
            }
        }
        float ps = ps2.x + ps2.y;
        ps += __shfl_xor(ps, 32);
        lrun += ps;

        // --- P repack: cvt_pk + permlane32_swap -> pan (consumed next iter) ---
        #pragma unroll
        for (int kb = 0; kb < 2; ++kb) {
            u32 wv[8];
            #pragma unroll
            for (int i = 0; i < 8; ++i)
                wv[i] = cvtpk(sacc[kb][2 * i], sacc[kb][2 * i + 1]);
            #pragma unroll
            for (int k2 = 0; k2 < 2; ++k2) {
                u32x2 r0 = __builtin_amdgcn_permlane32_swap(
                    wv[4 * k2 + 0], wv[4 * k2 + 2], false, false);
                u32x2 r1 = __builtin_amdgcn_permlane32_swap(
                    wv[4 * k2 + 1], wv[4 * k2 + 3], false, false);
                int g = kb * 2 + k2;
                pan[g * 4 + 0] = r0.x; pan[g * 4 + 1] = r1.x;
                pan[g * 4 + 2] = r0.y; pan[g * 4 + 3] = r1.y;
            }
        }
        __syncthreads();
    }

    // --- final PV(NT-1) ---
    {
        const int vprev = (NT - 1) % 3;
        #pragma unroll
        for (int g = 0; g < 4; ++g) {
            union { u32 u[4]; bf16x8 v; } pa;
            pa.u[0] = pan[g * 4 + 0]; pa.u[1] = pan[g * 4 + 1];
            pa.u[2] = pan[g * 4 + 2]; pa.u[3] = pan[g * 4 + 3];
            int kloc = g * 16 + hi * 8;
            #pragma unroll
            for (int dt = 0; dt < 4; ++dt) {
                int rowv = dt * 32 + lq;
                int byv  = rowv * 128 + ((kloc * 2) ^ ((rowv & 7) << 4));
                bf16x8 vf = *(const bf16x8*)&Vs[vprev][byv >> 1];
                oacc[dt] = __builtin_amdgcn_mfma_f32_32x32x16_bf16(
                    pa.v, vf, oacc[dt], 0, 0, 0);
            }
        }
    }

    // epilogue: O[q'][d], q' = (r&3)+8*(r>>2)+4*hi, d = dt*32+lq
    #pragma unroll
    for (int r = 0; r < 16; ++r) {
        int src = (r & 3) + 8 * (r >> 2) + 4 * hi;
        float linv = 1.f / __shfl(lrun, src);
        int s = q0 + src;
        size_t base = ((size_t)bb * S_ + s) * 2048 + h * 128 + lq;
        #pragma unroll
        for (int dt = 0; dt < 4; ++dt)
            AO[base + dt * 32] = f2bf(oacc[dt][r] * linv);
    }
}

// ---------------------------------------------------------------------------
extern "C" void kernel_launch(void* const* d_in, const int* in_sizes, int n_in,
                              void* d_out, int out_size, void* d_ws, size_t ws_size,
                              hipStream_t stream) {
    (void)in_sizes; (void)n_in; (void)out_size; (void)ws_size;
    const float* hid  = (const float*)d_in[0];
    const float* cosb = (const float*)d_in[1];
    const float* sinb = (const float*)d_in[2];
    const float* qw   = (const float*)d_in[3];
    const float* kw   = (const float*)d_in[4];
    const float* vw   = (const float*)d_in[5];
    const float* ow   = (const float*)d_in[6];
    const float* qnw  = (const float*)d_in[7];
    const float* knw  = (const float*)d_in[8];

    u16* ws   = (u16*)d_ws;
    u16* hidB = ws;                         // 8,388,608
    u16* Wc   = ws + 8388608;               // 6,291,456  (qw|kw|vw rows)
    u16* owB  = ws + 14680064;              // 4,194,304
    u16* Qb   = ws + 18874368;              // 8,388,608  [B*H][S][128]
    u16* Kb   = ws + 27262976;              // 2,097,152  [B*KVH][S][128]
    u16* VtB  = ws + 29360128;              // 2,097,152  [B*KVH][128][S]
    u16* AO   = ws + 31457280;              // 8,388,608  [B][S][2048]

    f2b_all<<<dim3(8192, 5), 256, 0, stream>>>(
        hid, hidB, 2097152,
        qw,  Wc,            1048576,
        kw,  Wc + 4194304,  262144,
        vw,  Wc + 5242880,  262144,
        ow,  owB,           1048576);

    gemm_bf16<0><<<dim3(24, 32), 256, 0, stream>>>(hidB, Wc, Qb, Kb, VtB, nullptr);
    norm_rope_k<<<4096, 256, 0, stream>>>(Kb, cosb, sinb, knw);
    attn_mfma<<<512, 256, 0, stream>>>(Qb, Kb, VtB, AO, cosb, sinb, qnw);
    gemm_bf16<1><<<dim3(16, 32), 256, 0, stream>>>(AO, owB, nullptr, nullptr, nullptr,
                                                   (float*)d_out);
}